// Round 2
// baseline (3331.870 us; speedup 1.0000x reference)
//
#include <hip/hip_runtime.h>
#include <hip/hip_bf16.h>

// Problem constants
#define B_ROWS 65536
#define D_IN   128
#define H_DIM  512
#define E_DIM  64
#define K_CODES 4096

// ---------------------------------------------------------------------------
// Generic fp32 GEMM: C[M,N] = act(A[M,K] @ W[K,N] * scale + shift)
// 256 threads, BMxBN tile, TMxTN per thread, BK k-chunk.
// ---------------------------------------------------------------------------
template<int BM, int BN, int BK, int TM, int TN, bool USE_SCALE, bool RELU, bool VEC_STORE>
__global__ __launch_bounds__(256)
void gemm_k(const float* __restrict__ A, const float* __restrict__ W,
            const float* __restrict__ scale, const float* __restrict__ shift,
            float* __restrict__ C, int M, int N, int K)
{
    constexpr int BMP = BM + 4;
    __shared__ __align__(16) float As[BK][BMP];
    __shared__ __align__(16) float Ws[BK][BN];
    constexpr int NTX = BN / TN;
    constexpr int NTY = BM / TM;
    static_assert(NTX * NTY == 256, "thread tiling mismatch");

    const int tid = threadIdx.x;
    const int tx = tid % NTX;
    const int ty = tid / NTX;
    const long m0 = (long)blockIdx.x * BM;
    const int  n0 = blockIdx.y * BN;

    constexpr int APASS = (BM * BK / 4) / 256;
    constexpr int WPASS = (BK * BN / 4) / 256;
    static_assert(APASS >= 1 && WPASS >= 1, "staging passes");

    float acc[TM][TN] = {};

    for (int k0 = 0; k0 < K; k0 += BK) {
        // stage A tile (transposed into LDS)
#pragma unroll
        for (int p = 0; p < APASS; ++p) {
            int qid = p * 256 + tid;
            int r = qid / (BK / 4);
            int c = (qid % (BK / 4)) * 4;
            float4 v = *(const float4*)(A + (m0 + r) * (long)K + (k0 + c));
            As[c + 0][r] = v.x; As[c + 1][r] = v.y;
            As[c + 2][r] = v.z; As[c + 3][r] = v.w;
        }
        // stage W tile
#pragma unroll
        for (int p = 0; p < WPASS; ++p) {
            int qid = p * 256 + tid;
            int r = qid / (BN / 4);
            int c = (qid % (BN / 4)) * 4;
            *(float4*)(&Ws[r][c]) = *(const float4*)(W + (long)(k0 + r) * N + (n0 + c));
        }
        __syncthreads();
#pragma unroll
        for (int kk = 0; kk < BK; ++kk) {
            float a[TM], w[TN];
#pragma unroll
            for (int i = 0; i < TM; i += 4) {
                float4 v = *(const float4*)(&As[kk][ty * TM + i]);
                a[i] = v.x; a[i + 1] = v.y; a[i + 2] = v.z; a[i + 3] = v.w;
            }
#pragma unroll
            for (int j = 0; j < TN; j += 4) {
                float4 v = *(const float4*)(&Ws[kk][tx * TN + j]);
                w[j] = v.x; w[j + 1] = v.y; w[j + 2] = v.z; w[j + 3] = v.w;
            }
#pragma unroll
            for (int i = 0; i < TM; ++i)
#pragma unroll
                for (int j = 0; j < TN; ++j)
                    acc[i][j] = fmaf(a[i], w[j], acc[i][j]);
        }
        __syncthreads();
    }

    // epilogue
#pragma unroll
    for (int i = 0; i < TM; ++i) {
        long row = m0 + ty * TM + i;
#pragma unroll
        for (int j = 0; j < TN; ++j) {
            int n = n0 + tx * TN + j;
            float v = acc[i][j];
            if (USE_SCALE) v *= scale[n];
            v += shift[n];
            if (RELU) v = fmaxf(v, 0.0f);
            acc[i][j] = v;
        }
        if (VEC_STORE) {
#pragma unroll
            for (int j = 0; j < TN; j += 4) {
                float4 v;
                v.x = acc[i][j]; v.y = acc[i][j + 1];
                v.z = acc[i][j + 2]; v.w = acc[i][j + 3];
                *(float4*)(C + row * (long)N + n0 + tx * TN + j) = v;
            }
        } else {
#pragma unroll
            for (int j = 0; j < TN; ++j)
                C[row * (long)N + n0 + tx * TN + j] = acc[i][j];
        }
    }
}

// ---------------------------------------------------------------------------
// Zero a u32 buffer (replaces hipMemsetAsync to avoid graph-capture doubt)
// ---------------------------------------------------------------------------
__global__ void zero_k(unsigned int* __restrict__ p, int n)
{
    int j = blockIdx.x * 256 + threadIdx.x;
    if (j < n) p[j] = 0u;
}

// ---------------------------------------------------------------------------
// Prep: fold BatchNorm into per-column scale/shift
// ---------------------------------------------------------------------------
__global__ void prep_bn(const float* __restrict__ b1, const float* __restrict__ g1,
                        const float* __restrict__ be1, const float* __restrict__ rm1,
                        const float* __restrict__ rv1,
                        float* __restrict__ s1, float* __restrict__ sh1)
{
    int j = blockIdx.x * 256 + threadIdx.x;
    if (j < H_DIM) {
        float s = g1[j] * (1.0f / sqrtf(rv1[j] + 1e-5f));
        s1[j] = s;
        sh1[j] = (b1[j] - rm1[j]) * s + be1[j];
    }
}

// ---------------------------------------------------------------------------
// Prep: L2-normalize codebook rows (one wave per row)
// ---------------------------------------------------------------------------
__global__ __launch_bounds__(256)
void prep_en(const float* __restrict__ emb, float* __restrict__ en)
{
    int lane = threadIdx.x & 63;
    int row = blockIdx.x * 4 + (threadIdx.x >> 6);
    float v = emb[(size_t)row * E_DIM + lane];
    float ss = v * v;
#pragma unroll
    for (int o = 32; o > 0; o >>= 1) ss += __shfl_xor(ss, o, 64);
    float n = fmaxf(sqrtf(ss), 1e-12f);
    en[(size_t)row * E_DIM + lane] = v / n;
}

// ---------------------------------------------------------------------------
// VQ argmin: block = 64 rows; 4 waves each scan codes c ≡ wave (mod 4).
// Tie-break = first min on dist = 2 - 2*dot, matching np.argmin.
// bi initialized to a VALID code so a NaN chain can never emit an OOB index.
// ---------------------------------------------------------------------------
__global__ __launch_bounds__(256)
void vq_argmin(const float* __restrict__ z, const float* __restrict__ en,
               int* __restrict__ idxb)
{
    __shared__ float zs[64][65];
    __shared__ float bdist[4][64];
    __shared__ int   bindx[4][64];
    const int tid = threadIdx.x;
    const int lane = tid & 63;
    const int wave = tid >> 6;
    const long r0 = (long)blockIdx.x * 64;

    for (int t = tid; t < 64 * 16; t += 256) {
        int rr = t >> 4, cq = (t & 15) << 2;
        float4 v = *(const float4*)(z + (r0 + rr) * E_DIM + cq);
        zs[rr][cq + 0] = v.x; zs[rr][cq + 1] = v.y;
        zs[rr][cq + 2] = v.z; zs[rr][cq + 3] = v.w;
    }
    __syncthreads();

    float zr[64];
    float ss = 0.f;
#pragma unroll
    for (int e = 0; e < 64; ++e) zr[e] = zs[lane][e];
#pragma unroll
    for (int e = 0; e < 64; ++e) ss += zr[e] * zr[e];
    float n = fmaxf(sqrtf(ss), 1e-12f);
#pragma unroll
    for (int e = 0; e < 64; ++e) zr[e] = zr[e] / n;

    const int w4 = __builtin_amdgcn_readfirstlane(wave);
    float best = 3.4028235e38f;
    int bi = w4;                      // valid code even if all dists are NaN
    for (int c = w4; c < K_CODES; c += 4) {
        const float* ep = en + (size_t)c * E_DIM;
        float dot = 0.f;
#pragma unroll
        for (int e = 0; e < 64; e += 4) {
            float4 wv = *(const float4*)(ep + e);
            dot = fmaf(zr[e + 0], wv.x, dot);
            dot = fmaf(zr[e + 1], wv.y, dot);
            dot = fmaf(zr[e + 2], wv.z, dot);
            dot = fmaf(zr[e + 3], wv.w, dot);
        }
        float dist = 2.0f - 2.0f * dot;
        if (dist < best) { best = dist; bi = c; }
    }
    bdist[wave][lane] = best;
    bindx[wave][lane] = bi;
    __syncthreads();
    if (wave == 0) {
        float bd = bdist[0][lane]; int b0 = bindx[0][lane];
#pragma unroll
        for (int w = 1; w < 4; ++w) {
            float d = bdist[w][lane]; int ii = bindx[w][lane];
            if (d < bd || (d == bd && ii < b0)) { bd = d; b0 = ii; }
        }
        idxb[r0 + lane] = b0;
    }
}

// ---------------------------------------------------------------------------
// Gather q = emb[idx], accumulate sum((q-z)^2), histogram counts,
// write q_ste (value == q) IN PLACE over z. One wave-lane per element.
// ---------------------------------------------------------------------------
__global__ __launch_bounds__(256)
void vq_gather(float* __restrict__ zq, const float* __restrict__ emb,
               const int* __restrict__ idxb,
               unsigned int* __restrict__ counts, float* __restrict__ sumsq)
{
    const int tid = threadIdx.x;
    const int lane = tid & 63;
    const int wave = tid >> 6;
    const long base = (long)blockIdx.x * 64;
    float local = 0.f;
    for (int r = wave; r < 64; r += 4) {
        long row = base + r;
        int i = idxb[row] & (K_CODES - 1);   // hard guard: never OOB
        float qv = emb[(size_t)i * E_DIM + lane];
        float zv = zq[row * E_DIM + lane];
        float d = qv - zv;
        local = fmaf(d, d, local);
        zq[row * E_DIM + lane] = zv + (qv - zv);  // q_ste value
        if (lane == 0) atomicAdd(&counts[i], 1u);
    }
    __shared__ float red[256];
    red[tid] = local;
    __syncthreads();
    for (int s = 128; s > 0; s >>= 1) {
        if (tid < s) red[tid] += red[tid + s];
        __syncthreads();
    }
    if (tid == 0) atomicAdd(sumsq, red[0]);
}

// ---------------------------------------------------------------------------
// Finalize: vq_loss and perplexity scalars
// ---------------------------------------------------------------------------
__global__ __launch_bounds__(1024)
void finalize_k(const unsigned int* __restrict__ counts, const float* __restrict__ sumsq,
                float* __restrict__ out_loss, float* __restrict__ out_perp)
{
    __shared__ float red[1024];
    const int tid = threadIdx.x;
    float local = 0.f;
    for (int i = tid; i < K_CODES; i += 1024) {
        float p = (float)counts[i] * (1.0f / (float)B_ROWS);
        local += p * logf(p + 1e-10f);
    }
    red[tid] = local;
    __syncthreads();
    for (int s = 512; s > 0; s >>= 1) {
        if (tid < s) red[tid] += red[tid + s];
        __syncthreads();
    }
    if (tid == 0) {
        out_loss[0] = 1.02f * (sumsq[0] * (1.0f / (float)(B_ROWS * (long)E_DIM)));
        out_perp[0] = expf(-red[0]);
    }
}

// ---------------------------------------------------------------------------
extern "C" void kernel_launch(void* const* d_in, const int* in_sizes, int n_in,
                              void* d_out, int out_size, void* d_ws, size_t ws_size,
                              hipStream_t stream)
{
    const float* x   = (const float*)d_in[0];
    const float* W1  = (const float*)d_in[1];
    const float* b1  = (const float*)d_in[2];
    const float* g1  = (const float*)d_in[3];
    const float* be1 = (const float*)d_in[4];
    const float* rm1 = (const float*)d_in[5];
    const float* rv1 = (const float*)d_in[6];
    const float* W2  = (const float*)d_in[7];
    const float* b2  = (const float*)d_in[8];
    const float* W3  = (const float*)d_in[9];
    const float* b3  = (const float*)d_in[10];
    const float* W4  = (const float*)d_in[11];
    const float* b4  = (const float*)d_in[12];
    const float* emb = (const float*)d_in[13];
    const float* Dw1 = (const float*)d_in[14];
    const float* db1 = (const float*)d_in[15];
    const float* Dw2 = (const float*)d_in[16];
    const float* db2 = (const float*)d_in[17];
    const float* Dw3 = (const float*)d_in[18];
    const float* db3 = (const float*)d_in[19];
    const float* Dw4 = (const float*)d_in[20];
    const float* db4 = (const float*)d_in[21];
    float* out = (float*)d_out;
    (void)in_sizes; (void)n_in;

    // ---- adaptive chunking: fit two CH x 512 ping-pong buffers in d_ws ----
    const size_t ws_floats = ws_size / sizeof(float);
    const size_t fixedf = (size_t)K_CODES * E_DIM /*en*/ + H_DIM /*s1*/ + H_DIM /*sh1*/
                        + K_CODES /*counts*/ + 16 /*sumsq pad*/;
    int CH = 128;
    for (int c = B_ROWS; c >= 128; c >>= 1) {
        size_t need = fixedf + (size_t)c /*idxb*/ + (size_t)c * 1024 /*X+Y*/;
        if (need <= ws_floats) { CH = c; break; }
    }

    // workspace layout (floats)
    float* X  = (float*)d_ws;                        // CH x 512 ping
    float* Y  = X + (size_t)CH * H_DIM;              // CH x 512 pong (also z/q: CH x 64)
    float* en = Y + (size_t)CH * H_DIM;              // 4096 x 64
    float* s1  = en + (size_t)K_CODES * E_DIM;       // 512
    float* sh1 = s1 + H_DIM;                         // 512
    unsigned int* counts = (unsigned int*)(sh1 + H_DIM);  // 4096 u32
    float* sumsq = (float*)(counts + K_CODES);       // 1 (+15 pad)
    int* idxb = (int*)(sumsq + 16);                  // CH ints

    zero_k<<<(K_CODES + 16 + 255) / 256, 256, 0, stream>>>(counts, K_CODES + 16);
    prep_bn<<<2, 256, 0, stream>>>(b1, g1, be1, rm1, rv1, s1, sh1);
    prep_en<<<K_CODES / 4, 256, 0, stream>>>(emb, en);

    dim3 blk(256);
    for (int c0 = 0; c0 < B_ROWS; c0 += CH) {
        const float* xc = x + (size_t)c0 * D_IN;
        const int M = CH;
        // encoder
        gemm_k<128,128,16,8,8,true ,true ,true ><<<dim3(M/128, 4), blk, 0, stream>>>(xc, W1, s1, sh1, X, M, 512, 128);
        gemm_k<128,128,16,8,8,false,true ,true ><<<dim3(M/128, 4), blk, 0, stream>>>(X, W2, nullptr, b2, Y, M, 512, 512);
        gemm_k<128,128,16,8,8,false,true ,true ><<<dim3(M/128, 2), blk, 0, stream>>>(Y, W3, nullptr, b3, X, M, 256, 512);
        gemm_k<128, 64,16,8,4,false,false,true ><<<dim3(M/128, 1), blk, 0, stream>>>(X, W4, nullptr, b4, Y, M,  64, 256);  // z -> Y

        // vector quantizer (z/q live at start of Y, CH x 64)
        vq_argmin<<<M / 64, 256, 0, stream>>>(Y, en, idxb);
        vq_gather<<<M / 64, 256, 0, stream>>>(Y, emb, idxb, counts, sumsq);

        // decoder (q in Y)
        gemm_k<128,128,16,8,8,false,true ,true ><<<dim3(M/128, 2), blk, 0, stream>>>(Y, Dw1, nullptr, db1, X, M, 256,  64);
        gemm_k<128,128,16,8,8,false,true ,true ><<<dim3(M/128, 4), blk, 0, stream>>>(X, Dw2, nullptr, db2, Y, M, 512, 256);
        gemm_k<128,128,16,8,8,false,true ,true ><<<dim3(M/128, 4), blk, 0, stream>>>(Y, Dw3, nullptr, db3, X, M, 512, 512);
        // x_recon to out+1 (+c0*128); misaligned for float4 -> scalar stores
        gemm_k<128,128,16,8,8,false,false,false><<<dim3(M/128, 1), blk, 0, stream>>>(X, Dw4, nullptr, db4, out + 1 + (size_t)c0 * D_IN, M, 128, 512);
    }

    // scalars: vq_loss at out[0], perplexity at out[out_size-1]
    finalize_k<<<1, 1024, 0, stream>>>(counts, sumsq, out, out + (out_size - 1));
}

// Round 3
// 606.033 us; speedup vs baseline: 5.4978x; 5.4978x over previous
//
#include <hip/hip_runtime.h>
#include <hip/hip_bf16.h>

#define B_ROWS 65536
#define D_IN   128
#define H_DIM  512
#define E_DIM  64
#define K_CODES 4096

typedef __bf16 bf16;
typedef __attribute__((ext_vector_type(8))) __bf16 bf16x8;
typedef __attribute__((ext_vector_type(4))) float f32x4;

// ---------------------------------------------------------------------------
// bf16 MFMA GEMM: C[M,N] = act(A[M,K] @ W[K,N] (*scale) + shift)
// A row-major bf16, WT = W^T row-major bf16 ([N][K], contiguous K).
// 256 thr = 4 waves in 2x2; wave = (BM/2)x(BN/2); 16x16x32 MFMA tiles.
// LDS rows padded to 40 bf16: frag ds_read_b128 is 2-way bank aliased (free).
// ---------------------------------------------------------------------------
template<int BM, int BN, bool OUT_F32, bool USE_SCALE, bool RELU>
__global__ __launch_bounds__(256)
void mfma_gemm(const bf16* __restrict__ A, const bf16* __restrict__ WT,
               const float* __restrict__ scale, const float* __restrict__ shift,
               void* __restrict__ Cout, int M, int N, int K)
{
    constexpr int LDT = 40;
    __shared__ bf16 As[BM * LDT];
    __shared__ bf16 Bs[BN * LDT];
    constexpr int MT = BM / 32;   // 16-row tiles per wave
    constexpr int NT = BN / 32;   // 16-col tiles per wave

    const int tid  = threadIdx.x;
    const int lane = tid & 63;
    const int wv   = tid >> 6;
    const int wm   = wv >> 1, wn = wv & 1;
    const int l16  = lane & 15, quad = lane >> 4;
    const long m0  = (long)blockIdx.x * BM;
    const int  n0  = blockIdx.y * BN;

    f32x4 acc[MT][NT] = {};

    for (int k0 = 0; k0 < K; k0 += 32) {
#pragma unroll
        for (int it = 0; it < (BM * 32) / (256 * 8); ++it) {
            int u = it * 256 + tid;
            int r = u >> 2;
            int cg = (u & 3) * 8;
            *(bf16x8*)&As[r * LDT + cg] = *(const bf16x8*)&A[(m0 + r) * (long)K + k0 + cg];
        }
#pragma unroll
        for (int it = 0; it < (BN * 32) / (256 * 8); ++it) {
            int u = it * 256 + tid;
            int r = u >> 2;
            int cg = (u & 3) * 8;
            *(bf16x8*)&Bs[r * LDT + cg] = *(const bf16x8*)&WT[(long)(n0 + r) * K + k0 + cg];
        }
        __syncthreads();
        bf16x8 af[MT], bfr[NT];
#pragma unroll
        for (int i = 0; i < MT; ++i)
            af[i] = *(const bf16x8*)&As[(wm * (BM / 2) + i * 16 + l16) * LDT + quad * 8];
#pragma unroll
        for (int j = 0; j < NT; ++j)
            bfr[j] = *(const bf16x8*)&Bs[(wn * (BN / 2) + j * 16 + l16) * LDT + quad * 8];
#pragma unroll
        for (int i = 0; i < MT; ++i)
#pragma unroll
            for (int j = 0; j < NT; ++j)
                acc[i][j] = __builtin_amdgcn_mfma_f32_16x16x32_bf16(af[i], bfr[j], acc[i][j], 0, 0, 0);
        __syncthreads();
    }

#pragma unroll
    for (int i = 0; i < MT; ++i) {
#pragma unroll
        for (int j = 0; j < NT; ++j) {
            int col = n0 + wn * (BN / 2) + j * 16 + l16;
            float sc = USE_SCALE ? scale[col] : 1.0f;
            float sh = shift[col];
#pragma unroll
            for (int r = 0; r < 4; ++r) {
                long row = m0 + wm * (BM / 2) + i * 16 + quad * 4 + r;
                float v = acc[i][j][r];
                if (USE_SCALE) v *= sc;
                v += sh;
                if (RELU) v = fmaxf(v, 0.0f);
                if (OUT_F32) ((float*)Cout)[row * (long)N + col] = v;
                else         ((bf16*)Cout)[row * (long)N + col] = (bf16)v;
            }
        }
    }
}

// ---------------------------------------------------------------------------
__global__ void zero_k(unsigned int* __restrict__ p, int n)
{
    int j = blockIdx.x * 256 + threadIdx.x;
    if (j < n) p[j] = 0u;
}

__global__ void prep_bn(const float* __restrict__ b1, const float* __restrict__ g1,
                        const float* __restrict__ be1, const float* __restrict__ rm1,
                        const float* __restrict__ rv1,
                        float* __restrict__ s1, float* __restrict__ sh1)
{
    int j = blockIdx.x * 256 + threadIdx.x;
    if (j < H_DIM) {
        float s = g1[j] * (1.0f / sqrtf(rv1[j] + 1e-5f));
        s1[j] = s;
        sh1[j] = (b1[j] - rm1[j]) * s + be1[j];
    }
}

// W[K,N] fp32 -> WT[N,K] bf16
__global__ void transp_w(const float* __restrict__ W, bf16* __restrict__ WT, int K, int N)
{
    long t = (long)blockIdx.x * 256 + threadIdx.x;
    if (t < (long)K * N) {
        int n = (int)(t / K), k = (int)(t % K);
        WT[t] = (bf16)W[(long)k * N + n];
    }
}

// fp32 -> bf16 elementwise (n multiple of 1024)
__global__ void conv_bf16(const float* __restrict__ in, bf16* __restrict__ out, long n)
{
    long i = ((long)blockIdx.x * 256 + threadIdx.x) * 4;
    if (i < n) {
        float4 v = *(const float4*)(in + i);
        out[i + 0] = (bf16)v.x; out[i + 1] = (bf16)v.y;
        out[i + 2] = (bf16)v.z; out[i + 3] = (bf16)v.w;
    }
}

// emb fp32 [K_CODES,64] -> L2-normalized bf16
__global__ __launch_bounds__(256)
void prep_en(const float* __restrict__ emb, bf16* __restrict__ en)
{
    int lane = threadIdx.x & 63;
    int row = blockIdx.x * 4 + (threadIdx.x >> 6);
    float v = emb[(size_t)row * E_DIM + lane];
    float ss = v * v;
#pragma unroll
    for (int o = 32; o > 0; o >>= 1) ss += __shfl_xor(ss, o, 64);
    float n = fmaxf(sqrtf(ss), 1e-12f);
    en[(size_t)row * E_DIM + lane] = (bf16)(v / n);
}

// z bf16 [M,64] -> L2-normalized bf16
__global__ __launch_bounds__(256)
void prep_zn(const bf16* __restrict__ z, bf16* __restrict__ zn)
{
    int lane = threadIdx.x & 63;
    long row = (long)blockIdx.x * 4 + (threadIdx.x >> 6);
    float v = (float)z[row * E_DIM + lane];
    float ss = v * v;
#pragma unroll
    for (int o = 32; o > 0; o >>= 1) ss += __shfl_xor(ss, o, 64);
    float n = fmaxf(sqrtf(ss), 1e-12f);
    zn[row * E_DIM + lane] = (bf16)(v / n);
}

// ---------------------------------------------------------------------------
// VQ argmin via MFMA: S = zn @ en^T, fused running argmax(dot) epilogue.
// Block = 4 waves x 16 rows = 64 rows; codebook staged in LDS 128 codes/chunk.
// argmin dist = argmax dot; ties -> smallest index (np.argmin first-min).
// ---------------------------------------------------------------------------
__global__ __launch_bounds__(256)
void vq_argmin_mfma(const bf16* __restrict__ zn, const bf16* __restrict__ en,
                    int* __restrict__ idxb)
{
    __shared__ bf16 es[128 * 72];   // 72 = 64 + 8 pad (2-way bank alias, free)
    const int tid = threadIdx.x;
    const int lane = tid & 63;
    const int wv = tid >> 6;
    const int l16 = lane & 15, quad = lane >> 4;
    const long r0 = (long)blockIdx.x * 64;
    const long arow = r0 + wv * 16 + l16;

    bf16x8 a0 = *(const bf16x8*)&zn[arow * E_DIM + quad * 8];
    bf16x8 a1 = *(const bf16x8*)&zn[arow * E_DIM + 32 + quad * 8];

    float best[4] = {-1e30f, -1e30f, -1e30f, -1e30f};
    int   bidx[4] = {0, 0, 0, 0};

    for (int c0 = 0; c0 < K_CODES; c0 += 128) {
#pragma unroll
        for (int it = 0; it < 4; ++it) {
            int u = it * 256 + tid;
            int r = u >> 3;
            int cg = (u & 7) * 8;
            *(bf16x8*)&es[r * 72 + cg] = *(const bf16x8*)&en[(long)(c0 + r) * E_DIM + cg];
        }
        __syncthreads();
#pragma unroll
        for (int cc = 0; cc < 8; ++cc) {
            bf16x8 b0 = *(const bf16x8*)&es[(cc * 16 + l16) * 72 + quad * 8];
            bf16x8 b1 = *(const bf16x8*)&es[(cc * 16 + l16) * 72 + 32 + quad * 8];
            f32x4 acc = {0.f, 0.f, 0.f, 0.f};
            acc = __builtin_amdgcn_mfma_f32_16x16x32_bf16(a0, b0, acc, 0, 0, 0);
            acc = __builtin_amdgcn_mfma_f32_16x16x32_bf16(a1, b1, acc, 0, 0, 0);
            int code = c0 + cc * 16 + l16;
#pragma unroll
            for (int r = 0; r < 4; ++r)
                if (acc[r] > best[r]) { best[r] = acc[r]; bidx[r] = code; }
        }
        __syncthreads();
    }
    // reduce over the 16 lanes of each quad-group (cols), rows = quad*4+r
#pragma unroll
    for (int off = 1; off < 16; off <<= 1) {
#pragma unroll
        for (int r = 0; r < 4; ++r) {
            float od = __shfl_xor(best[r], off, 64);
            int   oi = __shfl_xor(bidx[r], off, 64);
            if (od > best[r] || (od == best[r] && oi < bidx[r])) { best[r] = od; bidx[r] = oi; }
        }
    }
    if (l16 == 0) {
#pragma unroll
        for (int r = 0; r < 4; ++r)
            idxb[r0 + wv * 16 + quad * 4 + r] = bidx[r];
    }
}

// ---------------------------------------------------------------------------
// Gather q = emb[idx] (fp32), write qb bf16 for decoder, accumulate
// sum((q - z)^2) and the histogram.
// ---------------------------------------------------------------------------
__global__ __launch_bounds__(256)
void vq_gather(const bf16* __restrict__ zb, bf16* __restrict__ qb,
               const float* __restrict__ emb, const int* __restrict__ idxb,
               unsigned int* __restrict__ counts, float* __restrict__ sumsq)
{
    const int tid = threadIdx.x;
    const int lane = tid & 63;
    const int wave = tid >> 6;
    const long base = (long)blockIdx.x * 64;
    float local = 0.f;
    for (int r = wave; r < 64; r += 4) {
        long row = base + r;
        int i = idxb[row] & (K_CODES - 1);
        float qv = emb[(size_t)i * E_DIM + lane];
        float zv = (float)zb[row * E_DIM + lane];
        float d = qv - zv;
        local = fmaf(d, d, local);
        qb[row * E_DIM + lane] = (bf16)qv;
        if (lane == 0) atomicAdd(&counts[i], 1u);
    }
    __shared__ float red[256];
    red[tid] = local;
    __syncthreads();
    for (int s = 128; s > 0; s >>= 1) {
        if (tid < s) red[tid] += red[tid + s];
        __syncthreads();
    }
    if (tid == 0) atomicAdd(sumsq, red[0]);
}

// ---------------------------------------------------------------------------
__global__ __launch_bounds__(1024)
void finalize_k(const unsigned int* __restrict__ counts, const float* __restrict__ sumsq,
                float* __restrict__ out_loss, float* __restrict__ out_perp)
{
    __shared__ float red[1024];
    const int tid = threadIdx.x;
    float local = 0.f;
    for (int i = tid; i < K_CODES; i += 1024) {
        float p = (float)counts[i] * (1.0f / (float)B_ROWS);
        local += p * logf(p + 1e-10f);
    }
    red[tid] = local;
    __syncthreads();
    for (int s = 512; s > 0; s >>= 1) {
        if (tid < s) red[tid] += red[tid + s];
        __syncthreads();
    }
    if (tid == 0) {
        out_loss[0] = 1.02f * (sumsq[0] * (1.0f / (float)(B_ROWS * (long)E_DIM)));
        out_perp[0] = expf(-red[0]);
    }
}

// ---------------------------------------------------------------------------
extern "C" void kernel_launch(void* const* d_in, const int* in_sizes, int n_in,
                              void* d_out, int out_size, void* d_ws, size_t ws_size,
                              hipStream_t stream)
{
    const float* x   = (const float*)d_in[0];
    const float* W1  = (const float*)d_in[1];
    const float* b1  = (const float*)d_in[2];
    const float* g1  = (const float*)d_in[3];
    const float* be1 = (const float*)d_in[4];
    const float* rm1 = (const float*)d_in[5];
    const float* rv1 = (const float*)d_in[6];
    const float* W2  = (const float*)d_in[7];
    const float* b2  = (const float*)d_in[8];
    const float* W3  = (const float*)d_in[9];
    const float* b3  = (const float*)d_in[10];
    const float* W4  = (const float*)d_in[11];
    const float* b4  = (const float*)d_in[12];
    const float* emb = (const float*)d_in[13];
    const float* Dw1 = (const float*)d_in[14];
    const float* db1 = (const float*)d_in[15];
    const float* Dw2 = (const float*)d_in[16];
    const float* db2 = (const float*)d_in[17];
    const float* Dw3 = (const float*)d_in[18];
    const float* db3 = (const float*)d_in[19];
    const float* Dw4 = (const float*)d_in[20];
    const float* db4 = (const float*)d_in[21];
    float* out = (float*)d_out;
    (void)in_sizes; (void)n_in;

    // ---- workspace carve-up (256B-aligned byte offsets) ----
    char* p = (char*)d_ws;
    size_t off = 0;
    auto alloc = [&](size_t bytes) -> char* {
        char* r = p + off;
        off = (off + bytes + 255) & ~(size_t)255;
        return r;
    };
    bf16* en  = (bf16*)alloc((size_t)K_CODES * E_DIM * 2);
    bf16* W1T = (bf16*)alloc((size_t)D_IN * H_DIM * 2);
    bf16* W2T = (bf16*)alloc((size_t)H_DIM * H_DIM * 2);
    bf16* W3T = (bf16*)alloc((size_t)H_DIM * (H_DIM / 2) * 2);
    bf16* W4T = (bf16*)alloc((size_t)(H_DIM / 2) * E_DIM * 2);
    bf16* D1T = (bf16*)alloc((size_t)E_DIM * (H_DIM / 2) * 2);
    bf16* D2T = (bf16*)alloc((size_t)(H_DIM / 2) * H_DIM * 2);
    bf16* D3T = (bf16*)alloc((size_t)H_DIM * H_DIM * 2);
    bf16* D4T = (bf16*)alloc((size_t)H_DIM * D_IN * 2);
    float* s1  = (float*)alloc(H_DIM * 4);
    float* sh1 = (float*)alloc(H_DIM * 4);
    unsigned int* counts = (unsigned int*)alloc((K_CODES + 16) * 4);
    float* sumsq = (float*)(counts + K_CODES);
    size_t fixed_bytes = off;

    // per-chunk buffers: xb CH*128*2 + Xb CH*512*2 + Yb CH*512*2 + zb CH*64*2
    //                  + zn CH*64*2 + idxb CH*4  = CH*2564 B (+ alignment slack)
    int CH = 128;
    for (int c = B_ROWS; c >= 128; c >>= 1) {
        if (fixed_bytes + (size_t)c * 2564 + 2048 <= ws_size) { CH = c; break; }
    }
    bf16* xb = (bf16*)alloc((size_t)CH * D_IN * 2);
    bf16* Xb = (bf16*)alloc((size_t)CH * H_DIM * 2);
    bf16* Yb = (bf16*)alloc((size_t)CH * H_DIM * 2);
    bf16* zb = (bf16*)alloc((size_t)CH * E_DIM * 2);
    bf16* zn = (bf16*)alloc((size_t)CH * E_DIM * 2);
    int* idxb = (int*)alloc((size_t)CH * 4);
    bf16* qb = zn;  // reuse: zn dead after argmin

    // ---- prep (once) ----
    zero_k<<<(K_CODES + 16 + 255) / 256, 256, 0, stream>>>(counts, K_CODES + 16);
    prep_bn<<<2, 256, 0, stream>>>(b1, g1, be1, rm1, rv1, s1, sh1);
    prep_en<<<K_CODES / 4, 256, 0, stream>>>(emb, en);
    transp_w<<<(D_IN * H_DIM + 255) / 256, 256, 0, stream>>>(W1, W1T, D_IN, H_DIM);
    transp_w<<<(H_DIM * H_DIM + 255) / 256, 256, 0, stream>>>(W2, W2T, H_DIM, H_DIM);
    transp_w<<<(H_DIM * (H_DIM / 2) + 255) / 256, 256, 0, stream>>>(W3, W3T, H_DIM, H_DIM / 2);
    transp_w<<<((H_DIM / 2) * E_DIM + 255) / 256, 256, 0, stream>>>(W4, W4T, H_DIM / 2, E_DIM);
    transp_w<<<(E_DIM * (H_DIM / 2) + 255) / 256, 256, 0, stream>>>(Dw1, D1T, E_DIM, H_DIM / 2);
    transp_w<<<((H_DIM / 2) * H_DIM + 255) / 256, 256, 0, stream>>>(Dw2, D2T, H_DIM / 2, H_DIM);
    transp_w<<<(H_DIM * H_DIM + 255) / 256, 256, 0, stream>>>(Dw3, D3T, H_DIM, H_DIM);
    transp_w<<<(H_DIM * D_IN + 255) / 256, 256, 0, stream>>>(Dw4, D4T, H_DIM, D_IN);

    dim3 blk(256);
    for (int c0 = 0; c0 < B_ROWS; c0 += CH) {
        const int M = CH;
        conv_bf16<<<(M * D_IN / 4 + 255) / 256, 256, 0, stream>>>(x + (size_t)c0 * D_IN, xb, (long)M * D_IN);

        // encoder
        mfma_gemm<128,128,false,true ,true ><<<dim3(M/128, 4), blk, 0, stream>>>(xb, W1T, s1, sh1, Xb, M, 512, 128);
        mfma_gemm<128,128,false,false,true ><<<dim3(M/128, 4), blk, 0, stream>>>(Xb, W2T, nullptr, b2, Yb, M, 512, 512);
        mfma_gemm<128,128,false,false,true ><<<dim3(M/128, 2), blk, 0, stream>>>(Yb, W3T, nullptr, b3, Xb, M, 256, 512);
        mfma_gemm<128, 64,false,false,false><<<dim3(M/128, 1), blk, 0, stream>>>(Xb, W4T, nullptr, b4, zb, M,  64, 256);

        // vector quantizer
        prep_zn<<<M / 4, 256, 0, stream>>>(zb, zn);
        vq_argmin_mfma<<<M / 64, 256, 0, stream>>>(zn, en, idxb);
        vq_gather<<<M / 64, 256, 0, stream>>>(zb, qb, emb, idxb, counts, sumsq);

        // decoder
        mfma_gemm<128,128,false,false,true ><<<dim3(M/128, 2), blk, 0, stream>>>(qb, D1T, nullptr, db1, Xb, M, 256,  64);
        mfma_gemm<128,128,false,false,true ><<<dim3(M/128, 4), blk, 0, stream>>>(Xb, D2T, nullptr, db2, Yb, M, 512, 256);
        mfma_gemm<128,128,false,false,true ><<<dim3(M/128, 4), blk, 0, stream>>>(Yb, D3T, nullptr, db3, Xb, M, 512, 512);
        mfma_gemm<128,128,true ,false,false><<<dim3(M/128, 1), blk, 0, stream>>>(Xb, D4T, nullptr, db4, out + 1 + (size_t)c0 * D_IN, M, 128, 512);
    }

    finalize_k<<<1, 1024, 0, stream>>>(counts, sumsq, out, out + (out_size - 1));
}

// Round 4
// 485.305 us; speedup vs baseline: 6.8655x; 1.2488x over previous
//
#include <hip/hip_runtime.h>
#include <hip/hip_bf16.h>

#define B_ROWS 65536
#define D_IN   128
#define H_DIM  512
#define E_DIM  64
#define K_CODES 4096

typedef __bf16 bf16;
typedef __attribute__((ext_vector_type(8))) __bf16 bf16x8;
typedef __attribute__((ext_vector_type(4))) float f32x4;

// async global->LDS, 16 B per lane; LDS dest = wave-uniform base + lane*16
__device__ __forceinline__ void gld_lds16(const bf16* g, bf16* l)
{
    __builtin_amdgcn_global_load_lds((const __attribute__((address_space(1))) void*)g,
                                     (__attribute__((address_space(3))) void*)l,
                                     16, 0, 0);
}

// ---------------------------------------------------------------------------
// bf16 MFMA GEMM, BM=128 fixed. C[M,N] = act(A[M,K] @ W[K,N] (*scale) + shift)
// A row-major bf16; WT = W^T row-major ([N][K]). 4 waves in 2x2, wave tile
// 64 x (BN/2), 16x16x32 MFMA. Staging via global_load_lds (width 16).
// LDS layout unpadded 32-wide rows with XOR k-group swizzle:
//   slot c of row R holds k-group kg = c ^ ((R>>1)&3)
// -> frag ds_read_b128: each 16-lane phase hits every 4-bank group exactly 2x
//    (2-way aliasing = free), no 8-way conflicts.
// ---------------------------------------------------------------------------
template<int BN, bool OUT_F32, bool USE_SCALE, bool RELU>
__global__ __launch_bounds__(256)
void mfma_gemm(const bf16* __restrict__ A, const bf16* __restrict__ WT,
               const float* __restrict__ scale, const float* __restrict__ shift,
               void* __restrict__ Cout, int M, int N, int K)
{
    constexpr int BM = 128;
    constexpr int NT = BN / 32;        // 16-col tiles per wave
    constexpr int AISS = 8;            // (128*32 bf16) / (64 lanes * 8 bf16)
    constexpr int BISS = BN / 16;
    __shared__ bf16 As[BM * 32];
    __shared__ bf16 Bs[BN * 32];

    const int tid  = threadIdx.x;
    const int lane = tid & 63;
    const int wv   = tid >> 6;
    const int wm   = wv >> 1, wn = wv & 1;
    const int l16  = lane & 15, quad = lane >> 4;
    const size_t m0 = (size_t)blockIdx.x * BM;
    const int  n0  = blockIdx.y * BN;
    const int  csw = quad ^ ((l16 >> 1) & 3);   // read-side swizzled k-slot

    f32x4 acc[4][NT] = {};

    for (int k0 = 0; k0 < K; k0 += 32) {
#pragma unroll
        for (int ii = 0; ii < AISS / 4; ++ii) {
            int i = wv + ii * 4;
            int u = i * 64 + lane;
            int r = u >> 2;
            int kg = (u & 3) ^ ((r >> 1) & 3);
            gld_lds16(A + (m0 + r) * K + k0 + kg * 8, &As[i * 512]);
        }
#pragma unroll
        for (int ii = 0; ii < BISS / 4; ++ii) {
            int i = wv + ii * 4;
            int u = i * 64 + lane;
            int r = u >> 2;
            int kg = (u & 3) ^ ((r >> 1) & 3);
            gld_lds16(WT + (size_t)(n0 + r) * K + k0 + kg * 8, &Bs[i * 512]);
        }
        __syncthreads();
        bf16x8 af[4], bfr[NT];
#pragma unroll
        for (int i = 0; i < 4; ++i)
            af[i] = *(const bf16x8*)&As[(wm * 64 + i * 16 + l16) * 32 + csw * 8];
#pragma unroll
        for (int j = 0; j < NT; ++j)
            bfr[j] = *(const bf16x8*)&Bs[(wn * (BN / 2) + j * 16 + l16) * 32 + csw * 8];
#pragma unroll
        for (int i = 0; i < 4; ++i)
#pragma unroll
            for (int j = 0; j < NT; ++j)
                acc[i][j] = __builtin_amdgcn_mfma_f32_16x16x32_bf16(af[i], bfr[j], acc[i][j], 0, 0, 0);
        __syncthreads();
    }

#pragma unroll
    for (int i = 0; i < 4; ++i) {
#pragma unroll
        for (int j = 0; j < NT; ++j) {
            int col = n0 + wn * (BN / 2) + j * 16 + l16;
            float sc = USE_SCALE ? scale[col] : 1.0f;
            float sh = shift[col];
#pragma unroll
            for (int r = 0; r < 4; ++r) {
                size_t row = m0 + wm * 64 + i * 16 + quad * 4 + r;
                float v = acc[i][j][r];
                if (USE_SCALE) v *= sc;
                v += sh;
                if (RELU) v = fmaxf(v, 0.0f);
                if (OUT_F32) ((float*)Cout)[row * (size_t)N + col] = v;
                else         ((bf16*)Cout)[row * (size_t)N + col] = (bf16)v;
            }
        }
    }
}

// ---------------------------------------------------------------------------
__global__ void zero_k(unsigned int* __restrict__ p, int n)
{
    int j = blockIdx.x * 256 + threadIdx.x;
    if (j < n) p[j] = 0u;
}

__global__ void prep_bn(const float* __restrict__ b1, const float* __restrict__ g1,
                        const float* __restrict__ be1, const float* __restrict__ rm1,
                        const float* __restrict__ rv1,
                        float* __restrict__ s1, float* __restrict__ sh1)
{
    int j = blockIdx.x * 256 + threadIdx.x;
    if (j < H_DIM) {
        float s = g1[j] * (1.0f / sqrtf(rv1[j] + 1e-5f));
        s1[j] = s;
        sh1[j] = (b1[j] - rm1[j]) * s + be1[j];
    }
}

// ---------------------------------------------------------------------------
// All 8 weight transposes in one kernel: 64x64 LDS tiles, coalesced both ways.
// ---------------------------------------------------------------------------
struct TranspArgs { const float* s[8]; bf16* d[8]; };

__global__ __launch_bounds__(256)
void transp_all(TranspArgs a)
{
    // K (rows), N (cols) per segment; tiles = (K/64)*(N/64)
    constexpr int KS[8]  = {128, 512, 512, 256,  64, 256, 512, 512};
    constexpr int NS[8]  = {512, 512, 256,  64, 256, 512, 512, 128};
    constexpr int CUM[9] = {0, 16, 80, 112, 116, 120, 152, 216, 232};
    __shared__ float T[64][65];

    int bid = blockIdx.x;
    int seg = 0;
#pragma unroll
    for (int s = 0; s < 8; ++s)
        if (bid >= CUM[s + 1]) seg = s + 1;
    const int bt = bid - CUM[seg];
    const int K = KS[seg], N = NS[seg];
    const int tiles_n = N / 64;
    const int k0 = (bt / tiles_n) * 64;
    const int n0 = (bt % tiles_n) * 64;
    const float* src = a.s[seg];
    bf16* dst = a.d[seg];

    const int tid = threadIdx.x;
    const int rr = tid >> 6, cc = tid & 63;
#pragma unroll
    for (int p = 0; p < 16; ++p) {
        int row = p * 4 + rr;
        T[row][cc] = src[(size_t)(k0 + row) * N + n0 + cc];
    }
    __syncthreads();
#pragma unroll
    for (int p = 0; p < 16; ++p) {
        int row = p * 4 + rr;   // n-offset
        dst[(size_t)(n0 + row) * K + k0 + cc] = (bf16)T[cc][row];
    }
}

// fp32 -> bf16 elementwise
__global__ void conv_bf16(const float* __restrict__ in, bf16* __restrict__ out, long n)
{
    long i = ((long)blockIdx.x * 256 + threadIdx.x) * 4;
    if (i < n) {
        float4 v = *(const float4*)(in + i);
        out[i + 0] = (bf16)v.x; out[i + 1] = (bf16)v.y;
        out[i + 2] = (bf16)v.z; out[i + 3] = (bf16)v.w;
    }
}

// emb fp32 [K_CODES,64] -> L2-normalized bf16
__global__ __launch_bounds__(256)
void prep_en(const float* __restrict__ emb, bf16* __restrict__ en)
{
    int lane = threadIdx.x & 63;
    int row = blockIdx.x * 4 + (threadIdx.x >> 6);
    float v = emb[(size_t)row * E_DIM + lane];
    float ss = v * v;
#pragma unroll
    for (int o = 32; o > 0; o >>= 1) ss += __shfl_xor(ss, o, 64);
    float n = fmaxf(sqrtf(ss), 1e-12f);
    en[(size_t)row * E_DIM + lane] = (bf16)(v / n);
}

// z bf16 [M,64] -> L2-normalized bf16
__global__ __launch_bounds__(256)
void prep_zn(const bf16* __restrict__ z, bf16* __restrict__ zn)
{
    int lane = threadIdx.x & 63;
    long row = (long)blockIdx.x * 4 + (threadIdx.x >> 6);
    float v = (float)z[row * E_DIM + lane];
    float ss = v * v;
#pragma unroll
    for (int o = 32; o > 0; o >>= 1) ss += __shfl_xor(ss, o, 64);
    float n = fmaxf(sqrtf(ss), 1e-12f);
    zn[row * E_DIM + lane] = (bf16)(v / n);
}

// ---------------------------------------------------------------------------
// VQ argmin via MFMA (validated in R3): S = zn @ en^T, fused running argmax.
// ---------------------------------------------------------------------------
__global__ __launch_bounds__(256)
void vq_argmin_mfma(const bf16* __restrict__ zn, const bf16* __restrict__ en,
                    int* __restrict__ idxb)
{
    __shared__ bf16 es[128 * 72];
    const int tid = threadIdx.x;
    const int lane = tid & 63;
    const int wv = tid >> 6;
    const int l16 = lane & 15, quad = lane >> 4;
    const long r0 = (long)blockIdx.x * 64;
    const long arow = r0 + wv * 16 + l16;

    bf16x8 a0 = *(const bf16x8*)&zn[arow * E_DIM + quad * 8];
    bf16x8 a1 = *(const bf16x8*)&zn[arow * E_DIM + 32 + quad * 8];

    float best[4] = {-1e30f, -1e30f, -1e30f, -1e30f};
    int   bidx[4] = {0, 0, 0, 0};

    for (int c0 = 0; c0 < K_CODES; c0 += 128) {
#pragma unroll
        for (int it = 0; it < 4; ++it) {
            int u = it * 256 + tid;
            int r = u >> 3;
            int cg = (u & 7) * 8;
            *(bf16x8*)&es[r * 72 + cg] = *(const bf16x8*)&en[(long)(c0 + r) * E_DIM + cg];
        }
        __syncthreads();
#pragma unroll
        for (int cc = 0; cc < 8; ++cc) {
            bf16x8 b0 = *(const bf16x8*)&es[(cc * 16 + l16) * 72 + quad * 8];
            bf16x8 b1 = *(const bf16x8*)&es[(cc * 16 + l16) * 72 + 32 + quad * 8];
            f32x4 acc = {0.f, 0.f, 0.f, 0.f};
            acc = __builtin_amdgcn_mfma_f32_16x16x32_bf16(a0, b0, acc, 0, 0, 0);
            acc = __builtin_amdgcn_mfma_f32_16x16x32_bf16(a1, b1, acc, 0, 0, 0);
            int code = c0 + cc * 16 + l16;
#pragma unroll
            for (int r = 0; r < 4; ++r)
                if (acc[r] > best[r]) { best[r] = acc[r]; bidx[r] = code; }
        }
        __syncthreads();
    }
#pragma unroll
    for (int off = 1; off < 16; off <<= 1) {
#pragma unroll
        for (int r = 0; r < 4; ++r) {
            float od = __shfl_xor(best[r], off, 64);
            int   oi = __shfl_xor(bidx[r], off, 64);
            if (od > best[r] || (od == best[r] && oi < bidx[r])) { best[r] = od; bidx[r] = oi; }
        }
    }
    if (l16 == 0) {
#pragma unroll
        for (int r = 0; r < 4; ++r)
            idxb[r0 + wv * 16 + quad * 4 + r] = bidx[r];
    }
}

// ---------------------------------------------------------------------------
// VQ post: gather q=emb[idx] -> qb (bf16), sum((q-z)^2) -> psum[gblock]
// (non-atomic), LDS histogram -> dedup'd global u32 atomics (<=64/block).
// ---------------------------------------------------------------------------
__global__ __launch_bounds__(256)
void vq_post(const bf16* __restrict__ zb, bf16* __restrict__ qb,
             const float* __restrict__ emb, const int* __restrict__ idxb,
             unsigned int* __restrict__ counts, float* __restrict__ psum, int gb0)
{
    __shared__ unsigned hcnt[K_CODES];
    __shared__ float red[256];
    const int tid = threadIdx.x;
    const int lane = tid & 63;
    const int w = tid >> 6;
    const long base = (long)blockIdx.x * 64;

    for (int j = tid; j < K_CODES; j += 256) hcnt[j] = 0u;
    __syncthreads();
    if (tid < 64) atomicAdd(&hcnt[idxb[base + tid] & (K_CODES - 1)], 1u);

    float local = 0.f;
    int nid = idxb[base + w];
    for (int i = 0; i < 16; ++i) {
        long row = base + w + 4 * i;
        int id = nid & (K_CODES - 1);
        if (i < 15) nid = idxb[base + w + 4 * (i + 1)];
        float qv = emb[(size_t)id * E_DIM + lane];
        float zv = (float)zb[row * E_DIM + lane];
        float d = qv - zv;
        local = fmaf(d, d, local);
        qb[row * E_DIM + lane] = (bf16)qv;
    }
    red[tid] = local;
    __syncthreads();
    for (int s = 128; s > 0; s >>= 1) {
        if (tid < s) red[tid] += red[tid + s];
        __syncthreads();
    }
    if (tid == 0) psum[gb0 + blockIdx.x] = red[0];
    // hcnt final (barriers above); merge with one atomic per distinct code
    for (int j = tid; j < K_CODES; j += 256) {
        unsigned c = hcnt[j];
        if (c) atomicAdd(&counts[j], c);
    }
}

// ---------------------------------------------------------------------------
__global__ __launch_bounds__(1024)
void finalize_k(const unsigned int* __restrict__ counts, const float* __restrict__ psum,
                float* __restrict__ out_loss, float* __restrict__ out_perp)
{
    __shared__ float red[1024];
    const int tid = threadIdx.x;
    red[tid] = psum[tid];
    __syncthreads();
    for (int s = 512; s > 0; s >>= 1) {
        if (tid < s) red[tid] += red[tid + s];
        __syncthreads();
    }
    if (tid == 0)
        out_loss[0] = 1.02f * (red[0] * (1.0f / ((float)B_ROWS * (float)E_DIM)));
    __syncthreads();
    float e = 0.f;
    for (int j = tid; j < K_CODES; j += 1024) {
        float pr = (float)counts[j] * (1.0f / (float)B_ROWS);
        e += pr * logf(pr + 1e-10f);
    }
    red[tid] = e;
    __syncthreads();
    for (int s = 512; s > 0; s >>= 1) {
        if (tid < s) red[tid] += red[tid + s];
        __syncthreads();
    }
    if (tid == 0) out_perp[0] = expf(-red[0]);
}

// ---------------------------------------------------------------------------
extern "C" void kernel_launch(void* const* d_in, const int* in_sizes, int n_in,
                              void* d_out, int out_size, void* d_ws, size_t ws_size,
                              hipStream_t stream)
{
    const float* x   = (const float*)d_in[0];
    const float* W1  = (const float*)d_in[1];
    const float* b1  = (const float*)d_in[2];
    const float* g1  = (const float*)d_in[3];
    const float* be1 = (const float*)d_in[4];
    const float* rm1 = (const float*)d_in[5];
    const float* rv1 = (const float*)d_in[6];
    const float* W2  = (const float*)d_in[7];
    const float* b2  = (const float*)d_in[8];
    const float* W3  = (const float*)d_in[9];
    const float* b3  = (const float*)d_in[10];
    const float* W4  = (const float*)d_in[11];
    const float* b4  = (const float*)d_in[12];
    const float* emb = (const float*)d_in[13];
    const float* Dw1 = (const float*)d_in[14];
    const float* db1 = (const float*)d_in[15];
    const float* Dw2 = (const float*)d_in[16];
    const float* db2 = (const float*)d_in[17];
    const float* Dw3 = (const float*)d_in[18];
    const float* db3 = (const float*)d_in[19];
    const float* Dw4 = (const float*)d_in[20];
    const float* db4 = (const float*)d_in[21];
    float* out = (float*)d_out;
    (void)in_sizes; (void)n_in;

    // ---- workspace carve-up (256B-aligned) ----
    char* p = (char*)d_ws;
    size_t off = 0;
    auto alloc = [&](size_t bytes) -> char* {
        char* r = p + off;
        off = (off + bytes + 255) & ~(size_t)255;
        return r;
    };
    bf16* en  = (bf16*)alloc((size_t)K_CODES * E_DIM * 2);
    bf16* W1T = (bf16*)alloc((size_t)D_IN * H_DIM * 2);
    bf16* W2T = (bf16*)alloc((size_t)H_DIM * H_DIM * 2);
    bf16* W3T = (bf16*)alloc((size_t)H_DIM * (H_DIM / 2) * 2);
    bf16* W4T = (bf16*)alloc((size_t)(H_DIM / 2) * E_DIM * 2);
    bf16* D1T = (bf16*)alloc((size_t)E_DIM * (H_DIM / 2) * 2);
    bf16* D2T = (bf16*)alloc((size_t)(H_DIM / 2) * H_DIM * 2);
    bf16* D3T = (bf16*)alloc((size_t)H_DIM * H_DIM * 2);
    bf16* D4T = (bf16*)alloc((size_t)H_DIM * D_IN * 2);
    float* s1  = (float*)alloc(H_DIM * 4);
    float* sh1 = (float*)alloc(H_DIM * 4);
    unsigned int* counts = (unsigned int*)alloc(K_CODES * 4);
    float* psum = (float*)alloc((B_ROWS / 64) * 4);
    size_t fixed_bytes = off;

    // per-chunk: xb CH*256 + Xb CH*1024 + Yb CH*1024 + zb CH*128 + zn CH*128
    //          + idxb CH*4  = CH*2564 B
    int CH = 128;
    for (int c = B_ROWS; c >= 128; c >>= 1) {
        if (fixed_bytes + (size_t)c * 2564 + 4096 <= ws_size) { CH = c; break; }
    }
    bf16* xb = (bf16*)alloc((size_t)CH * D_IN * 2);
    bf16* Xb = (bf16*)alloc((size_t)CH * H_DIM * 2);
    bf16* Yb = (bf16*)alloc((size_t)CH * H_DIM * 2);
    bf16* zb = (bf16*)alloc((size_t)CH * E_DIM * 2);
    bf16* zn = (bf16*)alloc((size_t)CH * E_DIM * 2);
    int* idxb = (int*)alloc((size_t)CH * 4);
    bf16* qb = zn;  // zn dead after argmin

    // ---- prep (once) ----
    zero_k<<<(K_CODES + 255) / 256, 256, 0, stream>>>(counts, K_CODES);
    prep_bn<<<2, 256, 0, stream>>>(b1, g1, be1, rm1, rv1, s1, sh1);
    prep_en<<<K_CODES / 4, 256, 0, stream>>>(emb, en);
    TranspArgs ta;
    ta.s[0] = W1;  ta.d[0] = W1T;
    ta.s[1] = W2;  ta.d[1] = W2T;
    ta.s[2] = W3;  ta.d[2] = W3T;
    ta.s[3] = W4;  ta.d[3] = W4T;
    ta.s[4] = Dw1; ta.d[4] = D1T;
    ta.s[5] = Dw2; ta.d[5] = D2T;
    ta.s[6] = Dw3; ta.d[6] = D3T;
    ta.s[7] = Dw4; ta.d[7] = D4T;
    transp_all<<<232, 256, 0, stream>>>(ta);

    dim3 blk(256);
    for (int c0 = 0; c0 < B_ROWS; c0 += CH) {
        const int M = CH;
        conv_bf16<<<(M * D_IN / 4 + 255) / 256, 256, 0, stream>>>(x + (size_t)c0 * D_IN, xb, (long)M * D_IN);

        // encoder
        mfma_gemm<128,false,true ,true ><<<dim3(M/128, 4), blk, 0, stream>>>(xb, W1T, s1, sh1, Xb, M, 512, 128);
        mfma_gemm<128,false,false,true ><<<dim3(M/128, 4), blk, 0, stream>>>(Xb, W2T, nullptr, b2, Yb, M, 512, 512);
        mfma_gemm<128,false,false,true ><<<dim3(M/128, 2), blk, 0, stream>>>(Yb, W3T, nullptr, b3, Xb, M, 256, 512);
        mfma_gemm< 64,false,false,false><<<dim3(M/128, 1), blk, 0, stream>>>(Xb, W4T, nullptr, b4, zb, M,  64, 256);

        // vector quantizer
        prep_zn<<<M / 4, 256, 0, stream>>>(zb, zn);
        vq_argmin_mfma<<<M / 64, 256, 0, stream>>>(zn, en, idxb);
        vq_post<<<M / 64, 256, 0, stream>>>(zb, qb, emb, idxb, counts, psum, c0 / 64);

        // decoder
        mfma_gemm<128,false,false,true ><<<dim3(M/128, 2), blk, 0, stream>>>(qb, D1T, nullptr, db1, Xb, M, 256,  64);
        mfma_gemm<128,false,false,true ><<<dim3(M/128, 4), blk, 0, stream>>>(Xb, D2T, nullptr, db2, Yb, M, 512, 256);
        mfma_gemm<128,false,false,true ><<<dim3(M/128, 4), blk, 0, stream>>>(Yb, D3T, nullptr, db3, Xb, M, 512, 512);
        mfma_gemm<128,true ,false,false><<<dim3(M/128, 1), blk, 0, stream>>>(Xb, D4T, nullptr, db4, out + 1 + (size_t)c0 * D_IN, M, 128, 512);
    }

    finalize_k<<<1, 1024, 0, stream>>>(counts, psum, out, out + (out_size - 1));
}

// Round 5
// 448.431 us; speedup vs baseline: 7.4301x; 1.0822x over previous
//
#include <hip/hip_runtime.h>
#include <hip/hip_bf16.h>

#define B_ROWS 65536
#define D_IN   128
#define H_DIM  512
#define E_DIM  64
#define K_CODES 4096

typedef __bf16 bf16;
typedef __attribute__((ext_vector_type(8))) __bf16 bf16x8;
typedef __attribute__((ext_vector_type(4))) float f32x4;

// async global->LDS, 16 B per lane; LDS dest = wave-uniform base + lane*16
__device__ __forceinline__ void gld_lds16(const bf16* g, bf16* l)
{
    __builtin_amdgcn_global_load_lds((const __attribute__((address_space(1))) void*)g,
                                     (__attribute__((address_space(3))) void*)l,
                                     16, 0, 0);
}

// ---------------------------------------------------------------------------
// bf16 MFMA GEMM, BM=128, BK=32, single-barrier double-buffered K-loop.
// C[M,N] = act(A[M,K] @ W[K,N] (*scale) + shift).  WT = W^T [N][K].
// 4 waves 2x2, wave tile 64 x (BN/2), 16x16x32 MFMA.
// LDS rows 32-wide unpadded, XOR k-group swizzle: slot c of row R holds
// granule kg = c ^ ((R>>1)&3)  -> 2-way-only (free) read phases.
// FUSE_ZN (BN=64): also emit zn = 0.5 * z/||z|| (row norms via shfl + LDS).
// ---------------------------------------------------------------------------
template<int BN, bool OUT_F32, bool USE_SCALE, bool RELU, bool FUSE_ZN>
__global__ __launch_bounds__(256)
void mfma_gemm(const bf16* __restrict__ A, const bf16* __restrict__ WT,
               const float* __restrict__ scale, const float* __restrict__ shift,
               void* __restrict__ Cout, bf16* __restrict__ Zn,
               int M, int N, int K)
{
    constexpr int NT = BN / 32;
    __shared__ bf16 As[2][128 * 32];
    __shared__ bf16 Bs[2][BN * 32];
    __shared__ float nrm2[FUSE_ZN ? 256 : 1];

    const int tid  = threadIdx.x;
    const int lane = tid & 63;
    const int wv   = tid >> 6;
    const int wm   = wv >> 1, wn = wv & 1;
    const int l16  = lane & 15, quad = lane >> 4;
    const size_t m0 = (size_t)blockIdx.x * 128;
    const int  n0  = blockIdx.y * BN;
    const int  csw = quad ^ ((l16 >> 1) & 3);
    const int  nk  = K >> 5;

    auto stage = [&](int s, int k0) {
#pragma unroll
        for (int ii = 0; ii < 2; ++ii) {
            int i = wv + ii * 4;
            int u = i * 64 + lane;
            int r = u >> 2;
            int kg = (u & 3) ^ ((r >> 1) & 3);
            gld_lds16(A + (m0 + r) * K + k0 + kg * 8, &As[s][i * 512]);
        }
#pragma unroll
        for (int ii = 0; ii < BN / 64; ++ii) {
            int i = wv + ii * 4;
            int u = i * 64 + lane;
            int r = u >> 2;
            int kg = (u & 3) ^ ((r >> 1) & 3);
            gld_lds16(WT + (size_t)(n0 + r) * K + k0 + kg * 8, &Bs[s][i * 512]);
        }
    };

    f32x4 acc[4][NT] = {};
    stage(0, 0);
    for (int kt = 0; kt < nk; ++kt) {
        __syncthreads();
        if (kt + 1 < nk) stage((kt + 1) & 1, (kt + 1) * 32);
        const bf16* as = As[kt & 1];
        const bf16* bs = Bs[kt & 1];
        bf16x8 af[4], bfr[NT];
#pragma unroll
        for (int i = 0; i < 4; ++i)
            af[i] = *(const bf16x8*)&as[(wm * 64 + i * 16 + l16) * 32 + csw * 8];
#pragma unroll
        for (int j = 0; j < NT; ++j)
            bfr[j] = *(const bf16x8*)&bs[(wn * (BN / 2) + j * 16 + l16) * 32 + csw * 8];
#pragma unroll
        for (int i = 0; i < 4; ++i)
#pragma unroll
            for (int j = 0; j < NT; ++j)
                acc[i][j] = __builtin_amdgcn_mfma_f32_16x16x32_bf16(af[i], bfr[j], acc[i][j], 0, 0, 0);
    }

    if constexpr (FUSE_ZN) {
        // z = acc + shift; need row norms over all 64 cols (2 waves x 32 cols)
        float vv[4][2][4];
        float pp[4][4];
#pragma unroll
        for (int i = 0; i < 4; ++i)
#pragma unroll
            for (int r = 0; r < 4; ++r) {
                float s = 0.f;
#pragma unroll
                for (int j = 0; j < 2; ++j) {
                    int col = n0 + wn * 32 + j * 16 + l16;
                    float v = acc[i][j][r] + shift[col];
                    vv[i][j][r] = v;
                    s = fmaf(v, v, s);
                }
                pp[i][r] = s;
            }
#pragma unroll
        for (int off = 1; off < 16; off <<= 1)
#pragma unroll
            for (int i = 0; i < 4; ++i)
#pragma unroll
                for (int r = 0; r < 4; ++r)
                    pp[i][r] += __shfl_xor(pp[i][r], off, 64);
        if (l16 == 0) {
#pragma unroll
            for (int i = 0; i < 4; ++i)
#pragma unroll
                for (int r = 0; r < 4; ++r)
                    nrm2[wn * 128 + wm * 64 + i * 16 + quad * 4 + r] = pp[i][r];
        }
        __syncthreads();
#pragma unroll
        for (int i = 0; i < 4; ++i)
#pragma unroll
            for (int r = 0; r < 4; ++r) {
                int rl = wm * 64 + i * 16 + quad * 4 + r;
                float s2 = nrm2[rl] + nrm2[128 + rl];
                float rn = 0.5f / fmaxf(sqrtf(s2), 1e-12f);
                size_t row = m0 + rl;
#pragma unroll
                for (int j = 0; j < 2; ++j) {
                    int col = n0 + wn * 32 + j * 16 + l16;
                    float v = vv[i][j][r];
                    ((bf16*)Cout)[row * 64 + col] = (bf16)v;
                    Zn[row * 64 + col] = (bf16)(v * rn);
                }
            }
    } else {
#pragma unroll
        for (int i = 0; i < 4; ++i) {
#pragma unroll
            for (int j = 0; j < NT; ++j) {
                int col = n0 + wn * (BN / 2) + j * 16 + l16;
                float sc = USE_SCALE ? scale[col] : 1.0f;
                float sh = shift[col];
#pragma unroll
                for (int r = 0; r < 4; ++r) {
                    size_t row = m0 + wm * 64 + i * 16 + quad * 4 + r;
                    float v = acc[i][j][r];
                    if (USE_SCALE) v *= sc;
                    v += sh;
                    if (RELU) v = fmaxf(v, 0.0f);
                    if (OUT_F32) ((float*)Cout)[row * (size_t)N + col] = v;
                    else         ((bf16*)Cout)[row * (size_t)N + col] = (bf16)v;
                }
            }
        }
    }
}

// ---------------------------------------------------------------------------
// prep_misc: blocks 0..1023 -> en (L2-normalized bf16 codebook);
// 1024..1039 -> zero counts; 1040 -> BN fold.
// ---------------------------------------------------------------------------
__global__ __launch_bounds__(256)
void prep_misc(const float* __restrict__ emb, bf16* __restrict__ en,
               unsigned int* __restrict__ counts,
               const float* __restrict__ b1, const float* __restrict__ g1,
               const float* __restrict__ be1, const float* __restrict__ rm1,
               const float* __restrict__ rv1,
               float* __restrict__ s1, float* __restrict__ sh1)
{
    const int bid = blockIdx.x;
    const int tid = threadIdx.x;
    if (bid < 1024) {
        int lane = tid & 63;
        int row = bid * 4 + (tid >> 6);
        float v = emb[(size_t)row * E_DIM + lane];
        float ss = v * v;
#pragma unroll
        for (int o = 32; o > 0; o >>= 1) ss += __shfl_xor(ss, o, 64);
        float n = fmaxf(sqrtf(ss), 1e-12f);
        en[(size_t)row * E_DIM + lane] = (bf16)(v / n);
    } else if (bid < 1040) {
        counts[(bid - 1024) * 256 + tid] = 0u;
    } else {
        for (int j = tid; j < H_DIM; j += 256) {
            float s = g1[j] * (1.0f / sqrtf(rv1[j] + 1e-5f));
            s1[j] = s;
            sh1[j] = (b1[j] - rm1[j]) * s + be1[j];
        }
    }
}

// ---------------------------------------------------------------------------
// All 8 weight transposes: 64x64 LDS tiles, coalesced both directions.
// ---------------------------------------------------------------------------
struct TranspArgs { const float* s[8]; bf16* d[8]; };

__global__ __launch_bounds__(256)
void transp_all(TranspArgs a)
{
    constexpr int KS[8]  = {128, 512, 512, 256,  64, 256, 512, 512};
    constexpr int NS[8]  = {512, 512, 256,  64, 256, 512, 512, 128};
    constexpr int CUM[9] = {0, 16, 80, 112, 116, 120, 152, 216, 232};
    __shared__ float T[64][65];

    int bid = blockIdx.x;
    int seg = 0;
#pragma unroll
    for (int s = 0; s < 8; ++s)
        if (bid >= CUM[s + 1]) seg = s + 1;
    const int bt = bid - CUM[seg];
    const int K = KS[seg], N = NS[seg];
    const int tiles_n = N / 64;
    const int k0 = (bt / tiles_n) * 64;
    const int n0 = (bt % tiles_n) * 64;
    const float* src = a.s[seg];
    bf16* dst = a.d[seg];

    const int tid = threadIdx.x;
    const int rr = tid >> 6, cc = tid & 63;
#pragma unroll
    for (int p = 0; p < 16; ++p) {
        int row = p * 4 + rr;
        T[row][cc] = src[(size_t)(k0 + row) * N + n0 + cc];
    }
    __syncthreads();
#pragma unroll
    for (int p = 0; p < 16; ++p) {
        int row = p * 4 + rr;
        dst[(size_t)(n0 + row) * K + k0 + cc] = (bf16)T[cc][row];
    }
}

// fp32 -> bf16 elementwise
__global__ void conv_bf16(const float* __restrict__ in, bf16* __restrict__ out, long n)
{
    long i = ((long)blockIdx.x * 256 + threadIdx.x) * 4;
    if (i < n) {
        float4 v = *(const float4*)(in + i);
        out[i + 0] = (bf16)v.x; out[i + 1] = (bf16)v.y;
        out[i + 2] = (bf16)v.z; out[i + 3] = (bf16)v.w;
    }
}

// ---------------------------------------------------------------------------
// VQ argmin v2: S = zn @ en^T via MFMA; packed-uint argmax epilogue.
// zn is pre-scaled by 0.5 => dot in [-0.5,0.5]; acc init 1.5 => score in
// [1,2) > 0, so float bits are order-isomorphic. pack = (bits & ~0xFFF) |
// (4095-code): v_max_u32 = argmax with first-min tie-break.
// Codebook staged via global_load_lds, XOR swizzle slot = kg ^ (row&7),
// single-barrier double-buffered 128-code chunks.
// ---------------------------------------------------------------------------
__global__ __launch_bounds__(256)
void vq_argmin2(const bf16* __restrict__ zn, const bf16* __restrict__ en,
                int* __restrict__ idxb)
{
    __shared__ bf16 es[2][128 * 64];
    const int tid = threadIdx.x;
    const int lane = tid & 63;
    const int wv = tid >> 6;
    const int l16 = lane & 15, quad = lane >> 4;
    const long r0 = (long)blockIdx.x * 64;
    const long arow = r0 + wv * 16 + l16;

    bf16x8 a0 = *(const bf16x8*)&zn[arow * E_DIM + quad * 8];
    bf16x8 a1 = *(const bf16x8*)&zn[arow * E_DIM + 32 + quad * 8];

    auto stage = [&](int s, int c0) {
#pragma unroll
        for (int ii = 0; ii < 4; ++ii) {
            int i = wv + ii * 4;
            int u = i * 64 + lane;
            int r = u >> 3;
            int kg = (u & 7) ^ (r & 7);
            gld_lds16(en + (size_t)(c0 + r) * E_DIM + kg * 8, &es[s][i * 512]);
        }
    };

    unsigned best[4] = {0u, 0u, 0u, 0u};
    const unsigned MASKHI = 0xFFFFF000u;
    stage(0, 0);
    for (int c0 = 0; c0 < K_CODES; c0 += 128) {
        __syncthreads();
        if (c0 + 128 < K_CODES) stage(((c0 >> 7) + 1) & 1, c0 + 128);
        const bf16* e = es[(c0 >> 7) & 1];
#pragma unroll
        for (int cc = 0; cc < 8; ++cc) {
            int srow = cc * 16 + l16;
            bf16x8 b0 = *(const bf16x8*)&e[srow * 64 + ((quad ^ (srow & 7)) * 8)];
            bf16x8 b1 = *(const bf16x8*)&e[srow * 64 + (((quad + 4) ^ (srow & 7)) * 8)];
            f32x4 acc = {1.5f, 1.5f, 1.5f, 1.5f};
            acc = __builtin_amdgcn_mfma_f32_16x16x32_bf16(a0, b0, acc, 0, 0, 0);
            acc = __builtin_amdgcn_mfma_f32_16x16x32_bf16(a1, b1, acc, 0, 0, 0);
            unsigned inv = (unsigned)(4095 - (c0 + cc * 16 + l16));
#pragma unroll
            for (int r = 0; r < 4; ++r) {
                unsigned pk = (__float_as_uint(acc[r]) & MASKHI) | inv;
                best[r] = best[r] > pk ? best[r] : pk;
            }
        }
    }
#pragma unroll
    for (int off = 1; off < 16; off <<= 1) {
#pragma unroll
        for (int r = 0; r < 4; ++r) {
            unsigned o = (unsigned)__shfl_xor((int)best[r], off, 64);
            best[r] = best[r] > o ? best[r] : o;
        }
    }
    if (l16 == 0) {
#pragma unroll
        for (int r = 0; r < 4; ++r)
            idxb[r0 + wv * 16 + quad * 4 + r] = 4095 - (int)(best[r] & 0xFFFu);
    }
}

// ---------------------------------------------------------------------------
// VQ post: gather q=emb[idx] -> qb (bf16), sum((q-z)^2) -> psum[gblock],
// LDS histogram -> dedup'd global u32 atomics.
// ---------------------------------------------------------------------------
__global__ __launch_bounds__(256)
void vq_post(const bf16* __restrict__ zb, bf16* __restrict__ qb,
             const float* __restrict__ emb, const int* __restrict__ idxb,
             unsigned int* __restrict__ counts, float* __restrict__ psum, int gb0)
{
    __shared__ unsigned hcnt[K_CODES];
    __shared__ float red[256];
    const int tid = threadIdx.x;
    const int lane = tid & 63;
    const int w = tid >> 6;
    const long base = (long)blockIdx.x * 64;

    for (int j = tid; j < K_CODES; j += 256) hcnt[j] = 0u;
    __syncthreads();
    if (tid < 64) atomicAdd(&hcnt[idxb[base + tid] & (K_CODES - 1)], 1u);

    float local = 0.f;
    int nid = idxb[base + w];
    for (int i = 0; i < 16; ++i) {
        long row = base + w + 4 * i;
        int id = nid & (K_CODES - 1);
        if (i < 15) nid = idxb[base + w + 4 * (i + 1)];
        float qv = emb[(size_t)id * E_DIM + lane];
        float zv = (float)zb[row * E_DIM + lane];
        float d = qv - zv;
        local = fmaf(d, d, local);
        qb[row * E_DIM + lane] = (bf16)qv;
    }
    red[tid] = local;
    __syncthreads();
    for (int s = 128; s > 0; s >>= 1) {
        if (tid < s) red[tid] += red[tid + s];
        __syncthreads();
    }
    if (tid == 0) psum[gb0 + blockIdx.x] = red[0];
    for (int j = tid; j < K_CODES; j += 256) {
        unsigned c = hcnt[j];
        if (c) atomicAdd(&counts[j], c);
    }
}

// ---------------------------------------------------------------------------
__global__ __launch_bounds__(1024)
void finalize_k(const unsigned int* __restrict__ counts, const float* __restrict__ psum,
                float* __restrict__ out_loss, float* __restrict__ out_perp)
{
    __shared__ float red[1024];
    const int tid = threadIdx.x;
    red[tid] = psum[tid];
    __syncthreads();
    for (int s = 512; s > 0; s >>= 1) {
        if (tid < s) red[tid] += red[tid + s];
        __syncthreads();
    }
    if (tid == 0)
        out_loss[0] = 1.02f * (red[0] * (1.0f / ((float)B_ROWS * (float)E_DIM)));
    __syncthreads();
    float e = 0.f;
    for (int j = tid; j < K_CODES; j += 1024) {
        float pr = (float)counts[j] * (1.0f / (float)B_ROWS);
        e += pr * logf(pr + 1e-10f);
    }
    red[tid] = e;
    __syncthreads();
    for (int s = 512; s > 0; s >>= 1) {
        if (tid < s) red[tid] += red[tid + s];
        __syncthreads();
    }
    if (tid == 0) out_perp[0] = expf(-red[0]);
}

// ---------------------------------------------------------------------------
extern "C" void kernel_launch(void* const* d_in, const int* in_sizes, int n_in,
                              void* d_out, int out_size, void* d_ws, size_t ws_size,
                              hipStream_t stream)
{
    const float* x   = (const float*)d_in[0];
    const float* W1  = (const float*)d_in[1];
    const float* b1  = (const float*)d_in[2];
    const float* g1  = (const float*)d_in[3];
    const float* be1 = (const float*)d_in[4];
    const float* rm1 = (const float*)d_in[5];
    const float* rv1 = (const float*)d_in[6];
    const float* W2  = (const float*)d_in[7];
    const float* b2  = (const float*)d_in[8];
    const float* W3  = (const float*)d_in[9];
    const float* b3  = (const float*)d_in[10];
    const float* W4  = (const float*)d_in[11];
    const float* b4  = (const float*)d_in[12];
    const float* emb = (const float*)d_in[13];
    const float* Dw1 = (const float*)d_in[14];
    const float* db1 = (const float*)d_in[15];
    const float* Dw2 = (const float*)d_in[16];
    const float* db2 = (const float*)d_in[17];
    const float* Dw3 = (const float*)d_in[18];
    const float* db3 = (const float*)d_in[19];
    const float* Dw4 = (const float*)d_in[20];
    const float* db4 = (const float*)d_in[21];
    float* out = (float*)d_out;
    (void)in_sizes; (void)n_in;

    // ---- workspace carve-up (256B-aligned) ----
    char* p = (char*)d_ws;
    size_t off = 0;
    auto alloc = [&](size_t bytes) -> char* {
        char* r = p + off;
        off = (off + bytes + 255) & ~(size_t)255;
        return r;
    };
    bf16* en  = (bf16*)alloc((size_t)K_CODES * E_DIM * 2);
    bf16* W1T = (bf16*)alloc((size_t)D_IN * H_DIM * 2);
    bf16* W2T = (bf16*)alloc((size_t)H_DIM * H_DIM * 2);
    bf16* W3T = (bf16*)alloc((size_t)H_DIM * (H_DIM / 2) * 2);
    bf16* W4T = (bf16*)alloc((size_t)(H_DIM / 2) * E_DIM * 2);
    bf16* D1T = (bf16*)alloc((size_t)E_DIM * (H_DIM / 2) * 2);
    bf16* D2T = (bf16*)alloc((size_t)(H_DIM / 2) * H_DIM * 2);
    bf16* D3T = (bf16*)alloc((size_t)H_DIM * H_DIM * 2);
    bf16* D4T = (bf16*)alloc((size_t)H_DIM * D_IN * 2);
    float* s1  = (float*)alloc(H_DIM * 4);
    float* sh1 = (float*)alloc(H_DIM * 4);
    unsigned int* counts = (unsigned int*)alloc(K_CODES * 4);
    float* psum = (float*)alloc((B_ROWS / 64) * 4);
    size_t fixed_bytes = off;

    int CH = 128;
    for (int c = B_ROWS; c >= 128; c >>= 1) {
        if (fixed_bytes + (size_t)c * 2564 + 4096 <= ws_size) { CH = c; break; }
    }
    bf16* xb = (bf16*)alloc((size_t)CH * D_IN * 2);
    bf16* Xb = (bf16*)alloc((size_t)CH * H_DIM * 2);
    bf16* Yb = (bf16*)alloc((size_t)CH * H_DIM * 2);
    bf16* zb = (bf16*)alloc((size_t)CH * E_DIM * 2);
    bf16* zn = (bf16*)alloc((size_t)CH * E_DIM * 2);
    int* idxb = (int*)alloc((size_t)CH * 4);
    bf16* qb = zn;  // zn dead after argmin

    // ---- prep (once) ----
    prep_misc<<<1041, 256, 0, stream>>>(emb, en, counts, b1, g1, be1, rm1, rv1, s1, sh1);
    TranspArgs ta;
    ta.s[0] = W1;  ta.d[0] = W1T;
    ta.s[1] = W2;  ta.d[1] = W2T;
    ta.s[2] = W3;  ta.d[2] = W3T;
    ta.s[3] = W4;  ta.d[3] = W4T;
    ta.s[4] = Dw1; ta.d[4] = D1T;
    ta.s[5] = Dw2; ta.d[5] = D2T;
    ta.s[6] = Dw3; ta.d[6] = D3T;
    ta.s[7] = Dw4; ta.d[7] = D4T;
    transp_all<<<232, 256, 0, stream>>>(ta);

    dim3 blk(256);
    for (int c0 = 0; c0 < B_ROWS; c0 += CH) {
        const int M = CH;
        conv_bf16<<<(M * D_IN / 4 + 255) / 256, 256, 0, stream>>>(x + (size_t)c0 * D_IN, xb, (long)M * D_IN);

        // encoder (W4 fused with zn = 0.5 * l2norm(z))
        mfma_gemm<128,false,true ,true ,false><<<dim3(M/128, 4), blk, 0, stream>>>(xb, W1T, s1, sh1, Xb, nullptr, M, 512, 128);
        mfma_gemm<128,false,false,true ,false><<<dim3(M/128, 4), blk, 0, stream>>>(Xb, W2T, nullptr, b2, Yb, nullptr, M, 512, 512);
        mfma_gemm<128,false,false,true ,false><<<dim3(M/128, 2), blk, 0, stream>>>(Yb, W3T, nullptr, b3, Xb, nullptr, M, 256, 512);
        mfma_gemm< 64,false,false,false,true ><<<dim3(M/128, 1), blk, 0, stream>>>(Xb, W4T, nullptr, b4, zb, zn, M, 64, 256);

        // vector quantizer
        vq_argmin2<<<M / 64, 256, 0, stream>>>(zn, en, idxb);
        vq_post<<<M / 64, 256, 0, stream>>>(zb, qb, emb, idxb, counts, psum, c0 / 64);

        // decoder
        mfma_gemm<128,false,false,true ,false><<<dim3(M/128, 2), blk, 0, stream>>>(qb, D1T, nullptr, db1, Xb, nullptr, M, 256,  64);
        mfma_gemm<128,false,false,true ,false><<<dim3(M/128, 4), blk, 0, stream>>>(Xb, D2T, nullptr, db2, Yb, nullptr, M, 512, 256);
        mfma_gemm<128,false,false,true ,false><<<dim3(M/128, 4), blk, 0, stream>>>(Yb, D3T, nullptr, db3, Xb, nullptr, M, 512, 512);
        mfma_gemm<128,true ,false,false,false><<<dim3(M/128, 1), blk, 0, stream>>>(Xb, D4T, nullptr, db4, out + 1 + (size_t)c0 * D_IN, nullptr, M, 128, 512);
    }

    finalize_k<<<1, 1024, 0, stream>>>(counts, psum, out, out + (out_size - 1));
}

// Round 6
// 426.003 us; speedup vs baseline: 7.8212x; 1.0526x over previous
//
#include <hip/hip_runtime.h>
#include <hip/hip_bf16.h>

#define B_ROWS 65536
#define D_IN   128
#define H_DIM  512
#define E_DIM  64
#define K_CODES 4096

typedef __bf16 bf16;
typedef __attribute__((ext_vector_type(8))) __bf16 bf16x8;
typedef __attribute__((ext_vector_type(4))) float f32x4;

// async global->LDS, 16 B per lane; LDS dest = wave-uniform base + lane*16
__device__ __forceinline__ void gld_lds16(const bf16* g, bf16* l)
{
    __builtin_amdgcn_global_load_lds((const __attribute__((address_space(1))) void*)g,
                                     (__attribute__((address_space(3))) void*)l,
                                     16, 0, 0);
}

// ---------------------------------------------------------------------------
// bf16 MFMA GEMM, BM=128, BK=32, single-barrier double-buffered K-loop.
// C[M,N] = act(A[M,K] @ W[K,N] (*scale) + shift).  WT = W^T [N][K].
// 1-D grid of P*NCB blocks, XCD-aware swizzle: same-panel col-blocks are
// adjacent in loc and pinned to one XCD (bid%8 = XCD round-robin heuristic)
// so the A panel is HBM-fetched once per XCD and L2-served to the rest.
// LDS rows 32-wide unpadded, XOR k-group swizzle (2-way-only read phases).
// CONV_A: A is fp32, converted to bf16 during staging (VGPR path).
// FUSE_ZN (BN=64): also emit zn = 0.5 * z/||z||.
// ---------------------------------------------------------------------------
template<int BN, int NCB, bool CONV_A, bool OUT_F32, bool USE_SCALE, bool RELU, bool FUSE_ZN>
__global__ __launch_bounds__(256)
void mfma_gemm(const void* __restrict__ Ap, const bf16* __restrict__ WT,
               const float* __restrict__ scale, const float* __restrict__ shift,
               void* __restrict__ Cout, bf16* __restrict__ Zn,
               int M, int N, int K)
{
    constexpr int NT = BN / 32;
    __shared__ bf16 As[2][128 * 32];
    __shared__ bf16 Bs[2][BN * 32];
    __shared__ float nrm2[FUSE_ZN ? 256 : 1];

    const int tid  = threadIdx.x;
    const int lane = tid & 63;
    const int wv   = tid >> 6;
    const int wm   = wv >> 1, wn = wv & 1;
    const int l16  = lane & 15, quad = lane >> 4;

    // ---- XCD-aware panel/col mapping ----
    const int P = (int)gridDim.x / NCB;
    int panel, colb;
    if (NCB == 1 || (P & 7) != 0) {
        panel = (int)blockIdx.x % P;
        colb  = (int)blockIdx.x / P;
    } else {
        int xcd = (int)blockIdx.x & 7;
        int loc = (int)blockIdx.x >> 3;
        panel = xcd * (P >> 3) + loc / NCB;
        colb  = loc % NCB;
    }
    const size_t m0 = (size_t)panel * 128;
    const int  n0  = colb * BN;
    const int  csw = quad ^ ((l16 >> 1) & 3);
    const int  nk  = K >> 5;

    auto stage = [&](int s, int k0) {
        if constexpr (CONV_A) {
            const float* Af = (const float*)Ap;
#pragma unroll
            for (int ii = 0; ii < 2; ++ii) {
                int u = (wv + ii * 4) * 64 + lane;
                int r = u >> 2;
                int kg = (u & 3) ^ ((r >> 1) & 3);
                const float* src = Af + (m0 + r) * K + k0 + kg * 8;
                float4 v0 = *(const float4*)src;
                float4 v1 = *(const float4*)(src + 4);
                bf16 t[8] = {(bf16)v0.x, (bf16)v0.y, (bf16)v0.z, (bf16)v0.w,
                             (bf16)v1.x, (bf16)v1.y, (bf16)v1.z, (bf16)v1.w};
                *(bf16x8*)&As[s][u * 8] = *(bf16x8*)t;
            }
        } else {
            const bf16* Ab = (const bf16*)Ap;
#pragma unroll
            for (int ii = 0; ii < 2; ++ii) {
                int i = wv + ii * 4;
                int u = i * 64 + lane;
                int r = u >> 2;
                int kg = (u & 3) ^ ((r >> 1) & 3);
                gld_lds16(Ab + (m0 + r) * K + k0 + kg * 8, &As[s][i * 512]);
            }
        }
#pragma unroll
        for (int ii = 0; ii < BN / 64; ++ii) {
            int i = wv + ii * 4;
            int u = i * 64 + lane;
            int r = u >> 2;
            int kg = (u & 3) ^ ((r >> 1) & 3);
            gld_lds16(WT + (size_t)(n0 + r) * K + k0 + kg * 8, &Bs[s][i * 512]);
        }
    };

    f32x4 acc[4][NT] = {};
    stage(0, 0);
    for (int kt = 0; kt < nk; ++kt) {
        __syncthreads();
        if (kt + 1 < nk) stage((kt + 1) & 1, (kt + 1) * 32);
        const bf16* as = As[kt & 1];
        const bf16* bs = Bs[kt & 1];
        bf16x8 af[4], bfr[NT];
#pragma unroll
        for (int i = 0; i < 4; ++i)
            af[i] = *(const bf16x8*)&as[(wm * 64 + i * 16 + l16) * 32 + csw * 8];
#pragma unroll
        for (int j = 0; j < NT; ++j)
            bfr[j] = *(const bf16x8*)&bs[(wn * (BN / 2) + j * 16 + l16) * 32 + csw * 8];
#pragma unroll
        for (int i = 0; i < 4; ++i)
#pragma unroll
            for (int j = 0; j < NT; ++j)
                acc[i][j] = __builtin_amdgcn_mfma_f32_16x16x32_bf16(af[i], bfr[j], acc[i][j], 0, 0, 0);
    }

    if constexpr (FUSE_ZN) {
        float vv[4][2][4];
        float pp[4][4];
#pragma unroll
        for (int i = 0; i < 4; ++i)
#pragma unroll
            for (int r = 0; r < 4; ++r) {
                float s = 0.f;
#pragma unroll
                for (int j = 0; j < 2; ++j) {
                    int col = n0 + wn * 32 + j * 16 + l16;
                    float v = acc[i][j][r] + shift[col];
                    vv[i][j][r] = v;
                    s = fmaf(v, v, s);
                }
                pp[i][r] = s;
            }
#pragma unroll
        for (int off = 1; off < 16; off <<= 1)
#pragma unroll
            for (int i = 0; i < 4; ++i)
#pragma unroll
                for (int r = 0; r < 4; ++r)
                    pp[i][r] += __shfl_xor(pp[i][r], off, 64);
        if (l16 == 0) {
#pragma unroll
            for (int i = 0; i < 4; ++i)
#pragma unroll
                for (int r = 0; r < 4; ++r)
                    nrm2[wn * 128 + wm * 64 + i * 16 + quad * 4 + r] = pp[i][r];
        }
        __syncthreads();
#pragma unroll
        for (int i = 0; i < 4; ++i)
#pragma unroll
            for (int r = 0; r < 4; ++r) {
                int rl = wm * 64 + i * 16 + quad * 4 + r;
                float s2 = nrm2[rl] + nrm2[128 + rl];
                float rn = 0.5f / fmaxf(sqrtf(s2), 1e-12f);
                size_t row = m0 + rl;
#pragma unroll
                for (int j = 0; j < 2; ++j) {
                    int col = n0 + wn * 32 + j * 16 + l16;
                    float v = vv[i][j][r];
                    ((bf16*)Cout)[row * 64 + col] = (bf16)v;
                    Zn[row * 64 + col] = (bf16)(v * rn);
                }
            }
    } else {
#pragma unroll
        for (int i = 0; i < 4; ++i) {
#pragma unroll
            for (int j = 0; j < NT; ++j) {
                int col = n0 + wn * (BN / 2) + j * 16 + l16;
                float sc = USE_SCALE ? scale[col] : 1.0f;
                float sh = shift[col];
#pragma unroll
                for (int r = 0; r < 4; ++r) {
                    size_t row = m0 + wm * 64 + i * 16 + quad * 4 + r;
                    float v = acc[i][j][r];
                    if (USE_SCALE) v *= sc;
                    v += sh;
                    if (RELU) v = fmaxf(v, 0.0f);
                    if (OUT_F32) ((float*)Cout)[row * (size_t)N + col] = v;
                    else         ((bf16*)Cout)[row * (size_t)N + col] = (bf16)v;
                }
            }
        }
    }
}

// ---------------------------------------------------------------------------
// prep_misc: blocks 0..1023 -> en (L2-normalized bf16 codebook);
// 1024..1039 -> zero counts; 1040 -> BN fold.
// ---------------------------------------------------------------------------
__global__ __launch_bounds__(256)
void prep_misc(const float* __restrict__ emb, bf16* __restrict__ en,
               unsigned int* __restrict__ counts,
               const float* __restrict__ b1, const float* __restrict__ g1,
               const float* __restrict__ be1, const float* __restrict__ rm1,
               const float* __restrict__ rv1,
               float* __restrict__ s1, float* __restrict__ sh1)
{
    const int bid = blockIdx.x;
    const int tid = threadIdx.x;
    if (bid < 1024) {
        int lane = tid & 63;
        int row = bid * 4 + (tid >> 6);
        float v = emb[(size_t)row * E_DIM + lane];
        float ss = v * v;
#pragma unroll
        for (int o = 32; o > 0; o >>= 1) ss += __shfl_xor(ss, o, 64);
        float n = fmaxf(sqrtf(ss), 1e-12f);
        en[(size_t)row * E_DIM + lane] = (bf16)(v / n);
    } else if (bid < 1040) {
        counts[(bid - 1024) * 256 + tid] = 0u;
    } else {
        for (int j = tid; j < H_DIM; j += 256) {
            float s = g1[j] * (1.0f / sqrtf(rv1[j] + 1e-5f));
            s1[j] = s;
            sh1[j] = (b1[j] - rm1[j]) * s + be1[j];
        }
    }
}

// ---------------------------------------------------------------------------
// All 8 weight transposes: 64x64 LDS tiles, coalesced both directions.
// ---------------------------------------------------------------------------
struct TranspArgs { const float* s[8]; bf16* d[8]; };

__global__ __launch_bounds__(256)
void transp_all(TranspArgs a)
{
    constexpr int KS[8]  = {128, 512, 512, 256,  64, 256, 512, 512};
    constexpr int NS[8]  = {512, 512, 256,  64, 256, 512, 512, 128};
    constexpr int CUM[9] = {0, 16, 80, 112, 116, 120, 152, 216, 232};
    __shared__ float T[64][65];

    int bid = blockIdx.x;
    int seg = 0;
#pragma unroll
    for (int s = 0; s < 8; ++s)
        if (bid >= CUM[s + 1]) seg = s + 1;
    const int bt = bid - CUM[seg];
    const int K = KS[seg], N = NS[seg];
    const int tiles_n = N / 64;
    const int k0 = (bt / tiles_n) * 64;
    const int n0 = (bt % tiles_n) * 64;
    const float* src = a.s[seg];
    bf16* dst = a.d[seg];

    const int tid = threadIdx.x;
    const int rr = tid >> 6, cc = tid & 63;
#pragma unroll
    for (int p = 0; p < 16; ++p) {
        int row = p * 4 + rr;
        T[row][cc] = src[(size_t)(k0 + row) * N + n0 + cc];
    }
    __syncthreads();
#pragma unroll
    for (int p = 0; p < 16; ++p) {
        int row = p * 4 + rr;
        dst[(size_t)(n0 + row) * K + k0 + cc] = (bf16)T[cc][row];
    }
}

// ---------------------------------------------------------------------------
// VQ argmin v2 (validated R5): S = zn @ en^T via MFMA; packed-uint argmax.
// ---------------------------------------------------------------------------
__global__ __launch_bounds__(256)
void vq_argmin2(const bf16* __restrict__ zn, const bf16* __restrict__ en,
                int* __restrict__ idxb)
{
    __shared__ bf16 es[2][128 * 64];
    const int tid = threadIdx.x;
    const int lane = tid & 63;
    const int wv = tid >> 6;
    const int l16 = lane & 15, quad = lane >> 4;
    const long r0 = (long)blockIdx.x * 64;
    const long arow = r0 + wv * 16 + l16;

    bf16x8 a0 = *(const bf16x8*)&zn[arow * E_DIM + quad * 8];
    bf16x8 a1 = *(const bf16x8*)&zn[arow * E_DIM + 32 + quad * 8];

    auto stage = [&](int s, int c0) {
#pragma unroll
        for (int ii = 0; ii < 4; ++ii) {
            int i = wv + ii * 4;
            int u = i * 64 + lane;
            int r = u >> 3;
            int kg = (u & 7) ^ (r & 7);
            gld_lds16(en + (size_t)(c0 + r) * E_DIM + kg * 8, &es[s][i * 512]);
        }
    };

    unsigned best[4] = {0u, 0u, 0u, 0u};
    const unsigned MASKHI = 0xFFFFF000u;
    stage(0, 0);
    for (int c0 = 0; c0 < K_CODES; c0 += 128) {
        __syncthreads();
        if (c0 + 128 < K_CODES) stage(((c0 >> 7) + 1) & 1, c0 + 128);
        const bf16* e = es[(c0 >> 7) & 1];
#pragma unroll
        for (int cc = 0; cc < 8; ++cc) {
            int srow = cc * 16 + l16;
            bf16x8 b0 = *(const bf16x8*)&e[srow * 64 + ((quad ^ (srow & 7)) * 8)];
            bf16x8 b1 = *(const bf16x8*)&e[srow * 64 + (((quad + 4) ^ (srow & 7)) * 8)];
            f32x4 acc = {1.5f, 1.5f, 1.5f, 1.5f};
            acc = __builtin_amdgcn_mfma_f32_16x16x32_bf16(a0, b0, acc, 0, 0, 0);
            acc = __builtin_amdgcn_mfma_f32_16x16x32_bf16(a1, b1, acc, 0, 0, 0);
            unsigned inv = (unsigned)(4095 - (c0 + cc * 16 + l16));
#pragma unroll
            for (int r = 0; r < 4; ++r) {
                unsigned pk = (__float_as_uint(acc[r]) & MASKHI) | inv;
                best[r] = best[r] > pk ? best[r] : pk;
            }
        }
    }
#pragma unroll
    for (int off = 1; off < 16; off <<= 1) {
#pragma unroll
        for (int r = 0; r < 4; ++r) {
            unsigned o = (unsigned)__shfl_xor((int)best[r], off, 64);
            best[r] = best[r] > o ? best[r] : o;
        }
    }
    if (l16 == 0) {
#pragma unroll
        for (int r = 0; r < 4; ++r)
            idxb[r0 + wv * 16 + quad * 4 + r] = 4095 - (int)(best[r] & 0xFFFu);
    }
}

// ---------------------------------------------------------------------------
// VQ post: gather q=emb[idx] -> qb (bf16), sum((q-z)^2) -> psum[gblock],
// LDS histogram -> dedup'd global u32 atomics.
// ---------------------------------------------------------------------------
__global__ __launch_bounds__(256)
void vq_post(const bf16* __restrict__ zb, bf16* __restrict__ qb,
             const float* __restrict__ emb, const int* __restrict__ idxb,
             unsigned int* __restrict__ counts, float* __restrict__ psum, int gb0)
{
    __shared__ unsigned hcnt[K_CODES];
    __shared__ float red[256];
    const int tid = threadIdx.x;
    const int lane = tid & 63;
    const int w = tid >> 6;
    const long base = (long)blockIdx.x * 64;

    for (int j = tid; j < K_CODES; j += 256) hcnt[j] = 0u;
    __syncthreads();
    if (tid < 64) atomicAdd(&hcnt[idxb[base + tid] & (K_CODES - 1)], 1u);

    float local = 0.f;
    int nid = idxb[base + w];
    for (int i = 0; i < 16; ++i) {
        long row = base + w + 4 * i;
        int id = nid & (K_CODES - 1);
        if (i < 15) nid = idxb[base + w + 4 * (i + 1)];
        float qv = emb[(size_t)id * E_DIM + lane];
        float zv = (float)zb[row * E_DIM + lane];
        float d = qv - zv;
        local = fmaf(d, d, local);
        qb[row * E_DIM + lane] = (bf16)qv;
    }
    red[tid] = local;
    __syncthreads();
    for (int s = 128; s > 0; s >>= 1) {
        if (tid < s) red[tid] += red[tid + s];
        __syncthreads();
    }
    if (tid == 0) psum[gb0 + blockIdx.x] = red[0];
    for (int j = tid; j < K_CODES; j += 256) {
        unsigned c = hcnt[j];
        if (c) atomicAdd(&counts[j], c);
    }
}

// ---------------------------------------------------------------------------
__global__ __launch_bounds__(1024)
void finalize_k(const unsigned int* __restrict__ counts, const float* __restrict__ psum,
                float* __restrict__ out_loss, float* __restrict__ out_perp)
{
    __shared__ float red[1024];
    const int tid = threadIdx.x;
    red[tid] = psum[tid];
    __syncthreads();
    for (int s = 512; s > 0; s >>= 1) {
        if (tid < s) red[tid] += red[tid + s];
        __syncthreads();
    }
    if (tid == 0)
        out_loss[0] = 1.02f * (red[0] * (1.0f / ((float)B_ROWS * (float)E_DIM)));
    __syncthreads();
    float e = 0.f;
    for (int j = tid; j < K_CODES; j += 1024) {
        float pr = (float)counts[j] * (1.0f / (float)B_ROWS);
        e += pr * logf(pr + 1e-10f);
    }
    red[tid] = e;
    __syncthreads();
    for (int s = 512; s > 0; s >>= 1) {
        if (tid < s) red[tid] += red[tid + s];
        __syncthreads();
    }
    if (tid == 0) out_perp[0] = expf(-red[0]);
}

// ---------------------------------------------------------------------------
extern "C" void kernel_launch(void* const* d_in, const int* in_sizes, int n_in,
                              void* d_out, int out_size, void* d_ws, size_t ws_size,
                              hipStream_t stream)
{
    const float* x   = (const float*)d_in[0];
    const float* W1  = (const float*)d_in[1];
    const float* b1  = (const float*)d_in[2];
    const float* g1  = (const float*)d_in[3];
    const float* be1 = (const float*)d_in[4];
    const float* rm1 = (const float*)d_in[5];
    const float* rv1 = (const float*)d_in[6];
    const float* W2  = (const float*)d_in[7];
    const float* b2  = (const float*)d_in[8];
    const float* W3  = (const float*)d_in[9];
    const float* b3  = (const float*)d_in[10];
    const float* W4  = (const float*)d_in[11];
    const float* b4  = (const float*)d_in[12];
    const float* emb = (const float*)d_in[13];
    const float* Dw1 = (const float*)d_in[14];
    const float* db1 = (const float*)d_in[15];
    const float* Dw2 = (const float*)d_in[16];
    const float* db2 = (const float*)d_in[17];
    const float* Dw3 = (const float*)d_in[18];
    const float* db3 = (const float*)d_in[19];
    const float* Dw4 = (const float*)d_in[20];
    const float* db4 = (const float*)d_in[21];
    float* out = (float*)d_out;
    (void)in_sizes; (void)n_in;

    // ---- workspace carve-up (256B-aligned) ----
    char* p = (char*)d_ws;
    size_t off = 0;
    auto alloc = [&](size_t bytes) -> char* {
        char* r = p + off;
        off = (off + bytes + 255) & ~(size_t)255;
        return r;
    };
    bf16* en  = (bf16*)alloc((size_t)K_CODES * E_DIM * 2);
    bf16* W1T = (bf16*)alloc((size_t)D_IN * H_DIM * 2);
    bf16* W2T = (bf16*)alloc((size_t)H_DIM * H_DIM * 2);
    bf16* W3T = (bf16*)alloc((size_t)H_DIM * (H_DIM / 2) * 2);
    bf16* W4T = (bf16*)alloc((size_t)(H_DIM / 2) * E_DIM * 2);
    bf16* D1T = (bf16*)alloc((size_t)E_DIM * (H_DIM / 2) * 2);
    bf16* D2T = (bf16*)alloc((size_t)(H_DIM / 2) * H_DIM * 2);
    bf16* D3T = (bf16*)alloc((size_t)H_DIM * H_DIM * 2);
    bf16* D4T = (bf16*)alloc((size_t)H_DIM * D_IN * 2);
    float* s1  = (float*)alloc(H_DIM * 4);
    float* sh1 = (float*)alloc(H_DIM * 4);
    unsigned int* counts = (unsigned int*)alloc(K_CODES * 4);
    float* psum = (float*)alloc((B_ROWS / 64) * 4);
    size_t fixed_bytes = off;

    // per-chunk: Xb CH*1024 + Yb CH*1024 + zb CH*128 + zn CH*128 + idxb CH*4
    int CH = 128;
    for (int c = B_ROWS; c >= 128; c >>= 1) {
        if (fixed_bytes + (size_t)c * 2308 + 4096 <= ws_size) { CH = c; break; }
    }
    bf16* Xb = (bf16*)alloc((size_t)CH * H_DIM * 2);
    bf16* Yb = (bf16*)alloc((size_t)CH * H_DIM * 2);
    bf16* zb = (bf16*)alloc((size_t)CH * E_DIM * 2);
    bf16* zn = (bf16*)alloc((size_t)CH * E_DIM * 2);
    int* idxb = (int*)alloc((size_t)CH * 4);
    bf16* qb = zn;  // zn dead after argmin

    // ---- prep (once) ----
    prep_misc<<<1041, 256, 0, stream>>>(emb, en, counts, b1, g1, be1, rm1, rv1, s1, sh1);
    TranspArgs ta;
    ta.s[0] = W1;  ta.d[0] = W1T;
    ta.s[1] = W2;  ta.d[1] = W2T;
    ta.s[2] = W3;  ta.d[2] = W3T;
    ta.s[3] = W4;  ta.d[3] = W4T;
    ta.s[4] = Dw1; ta.d[4] = D1T;
    ta.s[5] = Dw2; ta.d[5] = D2T;
    ta.s[6] = Dw3; ta.d[6] = D3T;
    ta.s[7] = Dw4; ta.d[7] = D4T;
    transp_all<<<232, 256, 0, stream>>>(ta);

    dim3 blk(256);
    for (int c0 = 0; c0 < B_ROWS; c0 += CH) {
        const int M = CH;
        const int P = M / 128;

        // encoder (W1 converts x fp32->bf16 in staging; W4 fused with zn)
        mfma_gemm<128,4,true ,false,true ,true ,false><<<P * 4, blk, 0, stream>>>(x + (size_t)c0 * D_IN, W1T, s1, sh1, Xb, nullptr, M, 512, 128);
        mfma_gemm<128,4,false,false,false,true ,false><<<P * 4, blk, 0, stream>>>(Xb, W2T, nullptr, b2, Yb, nullptr, M, 512, 512);
        mfma_gemm<128,2,false,false,false,true ,false><<<P * 2, blk, 0, stream>>>(Yb, W3T, nullptr, b3, Xb, nullptr, M, 256, 512);
        mfma_gemm< 64,1,false,false,false,false,true ><<<P * 1, blk, 0, stream>>>(Xb, W4T, nullptr, b4, zb, zn, M, 64, 256);

        // vector quantizer
        vq_argmin2<<<M / 64, 256, 0, stream>>>(zn, en, idxb);
        vq_post<<<M / 64, 256, 0, stream>>>(zb, qb, emb, idxb, counts, psum, c0 / 64);

        // decoder
        mfma_gemm<128,2,false,false,false,true ,false><<<P * 2, blk, 0, stream>>>(qb, D1T, nullptr, db1, Xb, nullptr, M, 256,  64);
        mfma_gemm<128,4,false,false,false,true ,false><<<P * 4, blk, 0, stream>>>(Xb, D2T, nullptr, db2, Yb, nullptr, M, 512, 256);
        mfma_gemm<128,4,false,false,false,true ,false><<<P * 4, blk, 0, stream>>>(Yb, D3T, nullptr, db3, Xb, nullptr, M, 512, 512);
        mfma_gemm<128,1,false,true ,false,false,false><<<P * 1, blk, 0, stream>>>(Xb, D4T, nullptr, db4, out + 1 + (size_t)c0 * D_IN, nullptr, M, 128, 512);
    }

    finalize_k<<<1, 1024, 0, stream>>>(counts, psum, out, out + (out_size - 1));
}

// Round 7
// 375.399 us; speedup vs baseline: 8.8755x; 1.1348x over previous
//
#include <hip/hip_runtime.h>
#include <hip/hip_bf16.h>

#define B_ROWS 65536
#define D_IN   128
#define H_DIM  512
#define E_DIM  64
#define K_CODES 4096

typedef __bf16 bf16;
typedef __attribute__((ext_vector_type(8))) __bf16 bf16x8;
typedef __attribute__((ext_vector_type(4))) float f32x4;

// async global->LDS, 16 B per lane; LDS dest = wave-uniform base + lane*16
__device__ __forceinline__ void gld_lds16(const bf16* g, bf16* l)
{
    __builtin_amdgcn_global_load_lds((const __attribute__((address_space(1))) void*)g,
                                     (__attribute__((address_space(3))) void*)l,
                                     16, 0, 0);
}

// ---------------------------------------------------------------------------
// bf16 MFMA GEMM, BM=128, BK=32, single-barrier double-buffered K-loop.
// C[M,N] = act(A[M,K] @ W[K,N] (*scale) + shift).  WT = W^T [N][K].
// XCD-aware 1-D grid swizzle (same-panel col-blocks adjacent + XCD-pinned).
// LDS rows 32-wide unpadded, XOR k-group swizzle (2-way-only read phases).
// CONV_A: A is fp32, converted to bf16 during staging (VGPR path).
// FUSE_ZN (BN=64): also emit zn = 0.5 * z/||z||.
// ---------------------------------------------------------------------------
template<int BN, int NCB, bool CONV_A, bool OUT_F32, bool USE_SCALE, bool RELU, bool FUSE_ZN>
__global__ __launch_bounds__(256)
void mfma_gemm(const void* __restrict__ Ap, const bf16* __restrict__ WT,
               const float* __restrict__ scale, const float* __restrict__ shift,
               void* __restrict__ Cout, bf16* __restrict__ Zn,
               int M, int N, int K)
{
    constexpr int NT = BN / 32;
    __shared__ bf16 As[2][128 * 32];
    __shared__ bf16 Bs[2][BN * 32];
    __shared__ float nrm2[FUSE_ZN ? 256 : 1];

    const int tid  = threadIdx.x;
    const int lane = tid & 63;
    const int wv   = tid >> 6;
    const int wm   = wv >> 1, wn = wv & 1;
    const int l16  = lane & 15, quad = lane >> 4;

    // ---- XCD-aware panel/col mapping ----
    const int P = (int)gridDim.x / NCB;
    int panel, colb;
    if (NCB == 1 || (P & 7) != 0) {
        panel = (int)blockIdx.x % P;
        colb  = (int)blockIdx.x / P;
    } else {
        int xcd = (int)blockIdx.x & 7;
        int loc = (int)blockIdx.x >> 3;
        panel = xcd * (P >> 3) + loc / NCB;
        colb  = loc % NCB;
    }
    const size_t m0 = (size_t)panel * 128;
    const int  n0  = colb * BN;
    const int  csw = quad ^ ((l16 >> 1) & 3);
    const int  nk  = K >> 5;

    auto stage = [&](int s, int k0) {
        if constexpr (CONV_A) {
            const float* Af = (const float*)Ap;
#pragma unroll
            for (int ii = 0; ii < 2; ++ii) {
                int u = (wv + ii * 4) * 64 + lane;
                int r = u >> 2;
                int kg = (u & 3) ^ ((r >> 1) & 3);
                const float* src = Af + (m0 + r) * K + k0 + kg * 8;
                float4 v0 = *(const float4*)src;
                float4 v1 = *(const float4*)(src + 4);
                bf16 t[8] = {(bf16)v0.x, (bf16)v0.y, (bf16)v0.z, (bf16)v0.w,
                             (bf16)v1.x, (bf16)v1.y, (bf16)v1.z, (bf16)v1.w};
                *(bf16x8*)&As[s][u * 8] = *(bf16x8*)t;
            }
        } else {
            const bf16* Ab = (const bf16*)Ap;
#pragma unroll
            for (int ii = 0; ii < 2; ++ii) {
                int i = wv + ii * 4;
                int u = i * 64 + lane;
                int r = u >> 2;
                int kg = (u & 3) ^ ((r >> 1) & 3);
                gld_lds16(Ab + (m0 + r) * K + k0 + kg * 8, &As[s][i * 512]);
            }
        }
#pragma unroll
        for (int ii = 0; ii < BN / 64; ++ii) {
            int i = wv + ii * 4;
            int u = i * 64 + lane;
            int r = u >> 2;
            int kg = (u & 3) ^ ((r >> 1) & 3);
            gld_lds16(WT + (size_t)(n0 + r) * K + k0 + kg * 8, &Bs[s][i * 512]);
        }
    };

    f32x4 acc[4][NT] = {};
    stage(0, 0);
    for (int kt = 0; kt < nk; ++kt) {
        __syncthreads();
        if (kt + 1 < nk) stage((kt + 1) & 1, (kt + 1) * 32);
        const bf16* as = As[kt & 1];
        const bf16* bs = Bs[kt & 1];
        bf16x8 af[4], bfr[NT];
#pragma unroll
        for (int i = 0; i < 4; ++i)
            af[i] = *(const bf16x8*)&as[(wm * 64 + i * 16 + l16) * 32 + csw * 8];
#pragma unroll
        for (int j = 0; j < NT; ++j)
            bfr[j] = *(const bf16x8*)&bs[(wn * (BN / 2) + j * 16 + l16) * 32 + csw * 8];
#pragma unroll
        for (int i = 0; i < 4; ++i)
#pragma unroll
            for (int j = 0; j < NT; ++j)
                acc[i][j] = __builtin_amdgcn_mfma_f32_16x16x32_bf16(af[i], bfr[j], acc[i][j], 0, 0, 0);
    }

    if constexpr (FUSE_ZN) {
        float vv[4][2][4];
        float pp[4][4];
#pragma unroll
        for (int i = 0; i < 4; ++i)
#pragma unroll
            for (int r = 0; r < 4; ++r) {
                float s = 0.f;
#pragma unroll
                for (int j = 0; j < 2; ++j) {
                    int col = n0 + wn * 32 + j * 16 + l16;
                    float v = acc[i][j][r] + shift[col];
                    vv[i][j][r] = v;
                    s = fmaf(v, v, s);
                }
                pp[i][r] = s;
            }
#pragma unroll
        for (int off = 1; off < 16; off <<= 1)
#pragma unroll
            for (int i = 0; i < 4; ++i)
#pragma unroll
                for (int r = 0; r < 4; ++r)
                    pp[i][r] += __shfl_xor(pp[i][r], off, 64);
        if (l16 == 0) {
#pragma unroll
            for (int i = 0; i < 4; ++i)
#pragma unroll
                for (int r = 0; r < 4; ++r)
                    nrm2[wn * 128 + wm * 64 + i * 16 + quad * 4 + r] = pp[i][r];
        }
        __syncthreads();
#pragma unroll
        for (int i = 0; i < 4; ++i)
#pragma unroll
            for (int r = 0; r < 4; ++r) {
                int rl = wm * 64 + i * 16 + quad * 4 + r;
                float s2 = nrm2[rl] + nrm2[128 + rl];
                float rn = 0.5f / fmaxf(sqrtf(s2), 1e-12f);
                size_t row = m0 + rl;
#pragma unroll
                for (int j = 0; j < 2; ++j) {
                    int col = n0 + wn * 32 + j * 16 + l16;
                    float v = vv[i][j][r];
                    ((bf16*)Cout)[row * 64 + col] = (bf16)v;
                    Zn[row * 64 + col] = (bf16)(v * rn);
                }
            }
    } else {
#pragma unroll
        for (int i = 0; i < 4; ++i) {
#pragma unroll
            for (int j = 0; j < NT; ++j) {
                int col = n0 + wn * (BN / 2) + j * 16 + l16;
                float sc = USE_SCALE ? scale[col] : 1.0f;
                float sh = shift[col];
#pragma unroll
                for (int r = 0; r < 4; ++r) {
                    size_t row = m0 + wm * 64 + i * 16 + quad * 4 + r;
                    float v = acc[i][j][r];
                    if (USE_SCALE) v *= sc;
                    v += sh;
                    if (RELU) v = fmaxf(v, 0.0f);
                    if (OUT_F32) ((float*)Cout)[row * (size_t)N + col] = v;
                    else         ((bf16*)Cout)[row * (size_t)N + col] = (bf16)v;
                }
            }
        }
    }
}

// ---------------------------------------------------------------------------
// prep_misc: blocks 0..1023 -> en (L2-normalized bf16 codebook);
// 1024..1039 -> zero counts; 1040 -> BN fold.
// ---------------------------------------------------------------------------
__global__ __launch_bounds__(256)
void prep_misc(const float* __restrict__ emb, bf16* __restrict__ en,
               unsigned int* __restrict__ counts,
               const float* __restrict__ b1, const float* __restrict__ g1,
               const float* __restrict__ be1, const float* __restrict__ rm1,
               const float* __restrict__ rv1,
               float* __restrict__ s1, float* __restrict__ sh1)
{
    const int bid = blockIdx.x;
    const int tid = threadIdx.x;
    if (bid < 1024) {
        int lane = tid & 63;
        int row = bid * 4 + (tid >> 6);
        float v = emb[(size_t)row * E_DIM + lane];
        float ss = v * v;
#pragma unroll
        for (int o = 32; o > 0; o >>= 1) ss += __shfl_xor(ss, o, 64);
        float n = fmaxf(sqrtf(ss), 1e-12f);
        en[(size_t)row * E_DIM + lane] = (bf16)(v / n);
    } else if (bid < 1040) {
        counts[(bid - 1024) * 256 + tid] = 0u;
    } else {
        for (int j = tid; j < H_DIM; j += 256) {
            float s = g1[j] * (1.0f / sqrtf(rv1[j] + 1e-5f));
            s1[j] = s;
            sh1[j] = (b1[j] - rm1[j]) * s + be1[j];
        }
    }
}

// ---------------------------------------------------------------------------
// All 8 weight transposes: 64x64 LDS tiles, coalesced both directions.
// ---------------------------------------------------------------------------
struct TranspArgs { const float* s[8]; bf16* d[8]; };

__global__ __launch_bounds__(256)
void transp_all(TranspArgs a)
{
    constexpr int KS[8]  = {128, 512, 512, 256,  64, 256, 512, 512};
    constexpr int NS[8]  = {512, 512, 256,  64, 256, 512, 512, 128};
    constexpr int CUM[9] = {0, 16, 80, 112, 116, 120, 152, 216, 232};
    __shared__ float T[64][65];

    int bid = blockIdx.x;
    int seg = 0;
#pragma unroll
    for (int s = 0; s < 8; ++s)
        if (bid >= CUM[s + 1]) seg = s + 1;
    const int bt = bid - CUM[seg];
    const int K = KS[seg], N = NS[seg];
    const int tiles_n = N / 64;
    const int k0 = (bt / tiles_n) * 64;
    const int n0 = (bt % tiles_n) * 64;
    const float* src = a.s[seg];
    bf16* dst = a.d[seg];

    const int tid = threadIdx.x;
    const int rr = tid >> 6, cc = tid & 63;
#pragma unroll
    for (int p = 0; p < 16; ++p) {
        int row = p * 4 + rr;
        T[row][cc] = src[(size_t)(k0 + row) * N + n0 + cc];
    }
    __syncthreads();
#pragma unroll
    for (int p = 0; p < 16; ++p) {
        int row = p * 4 + rr;
        dst[(size_t)(n0 + row) * K + k0 + cc] = (bf16)T[cc][row];
    }
}

// ---------------------------------------------------------------------------
// vq_all: per 64-row block —
//  1) argmin via MFMA (S = zn @ en^T, packed-uint argmax, validated R5/R6),
//  2) idx -> LDS, LDS histogram,
//  3) post: sumsq((emb[idx] - z)^2) -> psum, scatter x_recon = XRcb[idx].
// ---------------------------------------------------------------------------
__global__ __launch_bounds__(256)
void vq_all(const bf16* __restrict__ zn, const bf16* __restrict__ zb,
            const bf16* __restrict__ en, const float* __restrict__ emb,
            const float* __restrict__ XR, float* __restrict__ xout,
            unsigned int* __restrict__ counts, float* __restrict__ psum, int gb0)
{
    __shared__ bf16 es[2][128 * 64];
    __shared__ unsigned hcnt[K_CODES];
    __shared__ int idxs[64];
    __shared__ float red[256];
    const int tid = threadIdx.x;
    const int lane = tid & 63;
    const int wv = tid >> 6;
    const int l16 = lane & 15, quad = lane >> 4;
    const long r0 = (long)blockIdx.x * 64;
    const long arow = r0 + wv * 16 + l16;

    bf16x8 a0 = *(const bf16x8*)&zn[arow * E_DIM + quad * 8];
    bf16x8 a1 = *(const bf16x8*)&zn[arow * E_DIM + 32 + quad * 8];

    auto stage = [&](int s, int c0) {
#pragma unroll
        for (int ii = 0; ii < 4; ++ii) {
            int i = wv + ii * 4;
            int u = i * 64 + lane;
            int r = u >> 3;
            int kg = (u & 7) ^ (r & 7);
            gld_lds16(en + (size_t)(c0 + r) * E_DIM + kg * 8, &es[s][i * 512]);
        }
    };

    for (int j = tid; j < K_CODES; j += 256) hcnt[j] = 0u;

    unsigned best[4] = {0u, 0u, 0u, 0u};
    const unsigned MASKHI = 0xFFFFF000u;
    stage(0, 0);
    for (int c0 = 0; c0 < K_CODES; c0 += 128) {
        __syncthreads();
        if (c0 + 128 < K_CODES) stage(((c0 >> 7) + 1) & 1, c0 + 128);
        const bf16* e = es[(c0 >> 7) & 1];
#pragma unroll
        for (int cc = 0; cc < 8; ++cc) {
            int srow = cc * 16 + l16;
            bf16x8 b0 = *(const bf16x8*)&e[srow * 64 + ((quad ^ (srow & 7)) * 8)];
            bf16x8 b1 = *(const bf16x8*)&e[srow * 64 + (((quad + 4) ^ (srow & 7)) * 8)];
            f32x4 acc = {1.5f, 1.5f, 1.5f, 1.5f};
            acc = __builtin_amdgcn_mfma_f32_16x16x32_bf16(a0, b0, acc, 0, 0, 0);
            acc = __builtin_amdgcn_mfma_f32_16x16x32_bf16(a1, b1, acc, 0, 0, 0);
            unsigned inv = (unsigned)(4095 - (c0 + cc * 16 + l16));
#pragma unroll
            for (int r = 0; r < 4; ++r) {
                unsigned pk = (__float_as_uint(acc[r]) & MASKHI) | inv;
                best[r] = best[r] > pk ? best[r] : pk;
            }
        }
    }
#pragma unroll
    for (int off = 1; off < 16; off <<= 1) {
#pragma unroll
        for (int r = 0; r < 4; ++r) {
            unsigned o = (unsigned)__shfl_xor((int)best[r], off, 64);
            best[r] = best[r] > o ? best[r] : o;
        }
    }
    if (l16 == 0) {
#pragma unroll
        for (int r = 0; r < 4; ++r) {
            int b = 4095 - (int)(best[r] & 0xFFFu);
            idxs[wv * 16 + quad * 4 + r] = b;
            atomicAdd(&hcnt[b], 1u);
        }
    }
    __syncthreads();

    // post phase: wave wv handles rows wv, wv+4, ...
    float local = 0.f;
#pragma unroll 4
    for (int i = 0; i < 16; ++i) {
        int rl = wv + 4 * i;
        long row = r0 + rl;
        int id = idxs[rl] & (K_CODES - 1);
        float qv = emb[(size_t)id * E_DIM + lane];
        float zv = (float)zb[row * E_DIM + lane];
        float d = qv - zv;
        local = fmaf(d, d, local);
        float2 xv = *(const float2*)(XR + (size_t)id * D_IN + 2 * lane);
        float* dst = xout + (size_t)row * D_IN + 2 * lane;
        dst[0] = xv.x;
        dst[1] = xv.y;
    }
    red[tid] = local;
    __syncthreads();
    for (int s = 128; s > 0; s >>= 1) {
        if (tid < s) red[tid] += red[tid + s];
        __syncthreads();
    }
    if (tid == 0) psum[gb0 + blockIdx.x] = red[0];
    for (int j = tid; j < K_CODES; j += 256) {
        unsigned c = hcnt[j];
        if (c) atomicAdd(&counts[j], c);
    }
}

// ---------------------------------------------------------------------------
__global__ __launch_bounds__(1024)
void finalize_k(const unsigned int* __restrict__ counts, const float* __restrict__ psum,
                float* __restrict__ out_loss, float* __restrict__ out_perp)
{
    __shared__ float red[1024];
    const int tid = threadIdx.x;
    red[tid] = psum[tid];
    __syncthreads();
    for (int s = 512; s > 0; s >>= 1) {
        if (tid < s) red[tid] += red[tid + s];
        __syncthreads();
    }
    if (tid == 0)
        out_loss[0] = 1.02f * (red[0] * (1.0f / ((float)B_ROWS * (float)E_DIM)));
    __syncthreads();
    float e = 0.f;
    for (int j = tid; j < K_CODES; j += 1024) {
        float pr = (float)counts[j] * (1.0f / (float)B_ROWS);
        e += pr * logf(pr + 1e-10f);
    }
    red[tid] = e;
    __syncthreads();
    for (int s = 512; s > 0; s >>= 1) {
        if (tid < s) red[tid] += red[tid + s];
        __syncthreads();
    }
    if (tid == 0) out_perp[0] = expf(-red[0]);
}

// ---------------------------------------------------------------------------
extern "C" void kernel_launch(void* const* d_in, const int* in_sizes, int n_in,
                              void* d_out, int out_size, void* d_ws, size_t ws_size,
                              hipStream_t stream)
{
    const float* x   = (const float*)d_in[0];
    const float* W1  = (const float*)d_in[1];
    const float* b1  = (const float*)d_in[2];
    const float* g1  = (const float*)d_in[3];
    const float* be1 = (const float*)d_in[4];
    const float* rm1 = (const float*)d_in[5];
    const float* rv1 = (const float*)d_in[6];
    const float* W2  = (const float*)d_in[7];
    const float* b2  = (const float*)d_in[8];
    const float* W3  = (const float*)d_in[9];
    const float* b3  = (const float*)d_in[10];
    const float* W4  = (const float*)d_in[11];
    const float* b4  = (const float*)d_in[12];
    const float* emb = (const float*)d_in[13];
    const float* Dw1 = (const float*)d_in[14];
    const float* db1 = (const float*)d_in[15];
    const float* Dw2 = (const float*)d_in[16];
    const float* db2 = (const float*)d_in[17];
    const float* Dw3 = (const float*)d_in[18];
    const float* db3 = (const float*)d_in[19];
    const float* Dw4 = (const float*)d_in[20];
    const float* db4 = (const float*)d_in[21];
    float* out = (float*)d_out;
    (void)in_sizes; (void)n_in;

    // ---- workspace carve-up (256B-aligned) ----
    char* p = (char*)d_ws;
    size_t off = 0;
    auto alloc = [&](size_t bytes) -> char* {
        char* r = p + off;
        off = (off + bytes + 255) & ~(size_t)255;
        return r;
    };
    bf16* en  = (bf16*)alloc((size_t)K_CODES * E_DIM * 2);
    bf16* W1T = (bf16*)alloc((size_t)D_IN * H_DIM * 2);
    bf16* W2T = (bf16*)alloc((size_t)H_DIM * H_DIM * 2);
    bf16* W3T = (bf16*)alloc((size_t)H_DIM * (H_DIM / 2) * 2);
    bf16* W4T = (bf16*)alloc((size_t)(H_DIM / 2) * E_DIM * 2);
    bf16* D1T = (bf16*)alloc((size_t)E_DIM * (H_DIM / 2) * 2);
    bf16* D2T = (bf16*)alloc((size_t)(H_DIM / 2) * H_DIM * 2);
    bf16* D3T = (bf16*)alloc((size_t)H_DIM * H_DIM * 2);
    bf16* D4T = (bf16*)alloc((size_t)H_DIM * D_IN * 2);
    float* s1  = (float*)alloc(H_DIM * 4);
    float* sh1 = (float*)alloc(H_DIM * 4);
    unsigned int* counts = (unsigned int*)alloc(K_CODES * 4);
    float* psum = (float*)alloc((B_ROWS / 64) * 4);
    // mini decoder-on-codebook buffers
    bf16*  XR1  = (bf16*)alloc((size_t)K_CODES * (H_DIM / 2) * 2);  // 4096x256
    bf16*  XR2  = (bf16*)alloc((size_t)K_CODES * H_DIM * 2);        // 4096x512
    bf16*  XR3  = (bf16*)alloc((size_t)K_CODES * H_DIM * 2);        // 4096x512
    float* XRcb = (float*)alloc((size_t)K_CODES * D_IN * 4);        // 4096x128 f32
    size_t fixed_bytes = off;

    // per-chunk: Xb CH*1024 + Yb CH*1024 + zb CH*128 + zn CH*128
    int CH = 128;
    for (int c = B_ROWS; c >= 128; c >>= 1) {
        if (fixed_bytes + (size_t)c * 2304 + 4096 <= ws_size) { CH = c; break; }
    }
    bf16* Xb = (bf16*)alloc((size_t)CH * H_DIM * 2);
    bf16* Yb = (bf16*)alloc((size_t)CH * H_DIM * 2);
    bf16* zb = (bf16*)alloc((size_t)CH * E_DIM * 2);
    bf16* zn = (bf16*)alloc((size_t)CH * E_DIM * 2);

    // ---- prep (once) ----
    prep_misc<<<1041, 256, 0, stream>>>(emb, en, counts, b1, g1, be1, rm1, rv1, s1, sh1);
    TranspArgs ta;
    ta.s[0] = W1;  ta.d[0] = W1T;
    ta.s[1] = W2;  ta.d[1] = W2T;
    ta.s[2] = W3;  ta.d[2] = W3T;
    ta.s[3] = W4;  ta.d[3] = W4T;
    ta.s[4] = Dw1; ta.d[4] = D1T;
    ta.s[5] = Dw2; ta.d[5] = D2T;
    ta.s[6] = Dw3; ta.d[6] = D3T;
    ta.s[7] = Dw4; ta.d[7] = D4T;
    transp_all<<<232, 256, 0, stream>>>(ta);

    dim3 blk(256);

    // ---- mini decoder chain on the 4096-row codebook (one-time) ----
    // XRcb[c] = dec(emb[c]); then x_recon[row] = XRcb[idx[row]] (q_ste == q
    // to ~1 ulp fp32, far below accepted tolerance).
    mfma_gemm<128,2,true ,false,false,true ,false><<<32 * 2, blk, 0, stream>>>(emb, D1T, nullptr, db1, XR1, nullptr, K_CODES, 256,  64);
    mfma_gemm<128,4,false,false,false,true ,false><<<32 * 4, blk, 0, stream>>>(XR1, D2T, nullptr, db2, XR2, nullptr, K_CODES, 512, 256);
    mfma_gemm<128,4,false,false,false,true ,false><<<32 * 4, blk, 0, stream>>>(XR2, D3T, nullptr, db3, XR3, nullptr, K_CODES, 512, 512);
    mfma_gemm<128,1,false,true ,false,false,false><<<32 * 1, blk, 0, stream>>>(XR3, D4T, nullptr, db4, XRcb, nullptr, K_CODES, 128, 512);

    for (int c0 = 0; c0 < B_ROWS; c0 += CH) {
        const int M = CH;
        const int P = M / 128;

        // encoder (W1 converts x fp32->bf16 in staging; W4 fused with zn)
        mfma_gemm<128,4,true ,false,true ,true ,false><<<P * 4, blk, 0, stream>>>(x + (size_t)c0 * D_IN, W1T, s1, sh1, Xb, nullptr, M, 512, 128);
        mfma_gemm<128,4,false,false,false,true ,false><<<P * 4, blk, 0, stream>>>(Xb, W2T, nullptr, b2, Yb, nullptr, M, 512, 512);
        mfma_gemm<128,2,false,false,false,true ,false><<<P * 2, blk, 0, stream>>>(Yb, W3T, nullptr, b3, Xb, nullptr, M, 256, 512);
        mfma_gemm< 64,1,false,false,false,false,true ><<<P * 1, blk, 0, stream>>>(Xb, W4T, nullptr, b4, zb, zn, M, 64, 256);

        // VQ: argmin + histogram + sumsq + x_recon scatter, one kernel
        vq_all<<<M / 64, 256, 0, stream>>>(zn, zb, en, emb, XRcb,
                                           out + 1 + (size_t)c0 * D_IN,
                                           counts, psum, c0 / 64);
    }

    finalize_k<<<1, 1024, 0, stream>>>(counts, psum, out, out + (out_size - 1));
}